// Round 3
// baseline (501.285 us; speedup 1.0000x reference)
//
#include <hip/hip_runtime.h>
#include <math.h>

typedef unsigned short ushort_t;
typedef __attribute__((ext_vector_type(8))) short short8;
typedef __attribute__((ext_vector_type(4))) float f32x4;

#define MFMA(a,b,c) __builtin_amdgcn_mfma_f32_16x16x32_bf16((a),(b),(c),0,0,0)

// Problem constants
#define BB 8
#define SS 1024
#define DD 512
#define HH 8
#define CC 64
#define PP 2047   // 2S-1

static __device__ __forceinline__ ushort_t f2bf(float f) {
    unsigned u = __float_as_uint(f);
    u += 0x7fffu + ((u >> 16) & 1u);       // RNE
    return (ushort_t)(u >> 16);
}
static __device__ __forceinline__ unsigned pack2(float a, float b) {
    return (unsigned)f2bf(a) | ((unsigned)f2bf(b) << 16);
}

// ---------------------------------------------------------------------------
// Cast kernel: fp32->bf16 for q/k/v/pos; transpose+cast for the 5 weights.
// ---------------------------------------------------------------------------
__global__ __launch_bounds__(256) void cast_kernel(
    const float* __restrict__ q, const float* __restrict__ k,
    const float* __restrict__ v, const float* __restrict__ pos,
    const float* __restrict__ Wq, const float* __restrict__ Wk,
    const float* __restrict__ Wv, const float* __restrict__ Wp,
    const float* __restrict__ Wo,
    ushort_t* __restrict__ xq, ushort_t* __restrict__ xk,
    ushort_t* __restrict__ xv, ushort_t* __restrict__ xpos,
    ushort_t* __restrict__ wt)
{
    __shared__ float T[64][65];
    const int bid = blockIdx.x, tid = threadIdx.x;
    if (bid < 3328) {
        const float* src; ushort_t* dst; size_t n; int lb;
        if (bid < 1024)      { src = q;   dst = xq;   n = 4194304; lb = bid; }
        else if (bid < 2048) { src = k;   dst = xk;   n = 4194304; lb = bid - 1024; }
        else if (bid < 3072) { src = v;   dst = xv;   n = 4194304; lb = bid - 2048; }
        else                 { src = pos; dst = xpos; n = 1048064; lb = bid - 3072; }
        size_t off = (size_t)lb * 4096 + (size_t)tid * 16;
        if (off < n) {
            float4 f0 = *(const float4*)(src + off);
            float4 f1 = *(const float4*)(src + off + 4);
            float4 f2 = *(const float4*)(src + off + 8);
            float4 f3 = *(const float4*)(src + off + 12);
            uint4 u0, u1;
            u0.x = pack2(f0.x, f0.y); u0.y = pack2(f0.z, f0.w);
            u0.z = pack2(f1.x, f1.y); u0.w = pack2(f1.z, f1.w);
            u1.x = pack2(f2.x, f2.y); u1.y = pack2(f2.z, f2.w);
            u1.z = pack2(f3.x, f3.y); u1.w = pack2(f3.z, f3.w);
            *(uint4*)(dst + off)     = u0;
            *(uint4*)(dst + off + 8) = u1;
        }
    } else {
        const int wi   = (bid - 3328) >> 6;      // which weight
        const int tile = (bid - 3328) & 63;
        const float* Wsrc = (wi == 0) ? Wq : (wi == 1) ? Wk : (wi == 2) ? Wv
                          : (wi == 3) ? Wp : Wo;
        ushort_t* Wdst = wt + (size_t)wi * 262144;
        const int tk0 = (tile >> 3) * 64, tn0 = (tile & 7) * 64;
        const int r = tid >> 2, c4 = (tid & 3) * 16;
        #pragma unroll
        for (int rep = 0; rep < 4; ++rep) {
            float4 f = *(const float4*)(Wsrc + (size_t)(tk0 + r) * 512 + tn0 + c4 + rep * 4);
            T[r][c4 + rep * 4 + 0] = f.x; T[r][c4 + rep * 4 + 1] = f.y;
            T[r][c4 + rep * 4 + 2] = f.z; T[r][c4 + rep * 4 + 3] = f.w;
        }
        __syncthreads();
        #pragma unroll
        for (int rep = 0; rep < 4; ++rep) {
            uint2 u;
            u.x = pack2(T[c4 + rep * 4 + 0][r], T[c4 + rep * 4 + 1][r]);
            u.y = pack2(T[c4 + rep * 4 + 2][r], T[c4 + rep * 4 + 3][r]);
            *(uint2*)(Wdst + (size_t)(tn0 + r) * 512 + tk0 + c4 + rep * 4) = u;
        }
    }
}

// ---------------------------------------------------------------------------
// LDS-free MFMA projection GEMM: Y = X[M,512] @ Wt^T (+bias), bf16 in.
// All fragments loaded directly from global (A: m=l16 row; B: n=l16 row of Wt).
// MODE 0: Q -> qu,qv bf16 [B,H,S,C];  1: K -> [B,H,S,C];  2: V -> V^T [BH,C,S]
// MODE 3: pos -> [H,P,C];  4: out-proj -> fp32 row-major
// Block: 64(M)x64(N), 256 thr (4 waves, wave owns 16 rows). No barriers.
// ---------------------------------------------------------------------------
template<int MODE>
__global__ __launch_bounds__(256) void proj_kernel(
    const ushort_t* __restrict__ X, const ushort_t* __restrict__ W,
    const float* __restrict__ b1, const float* __restrict__ b2,
    const float* __restrict__ b3,
    ushort_t* __restrict__ Y1, ushort_t* __restrict__ Y2,
    float* __restrict__ Yf)
{
    const int tid = threadIdx.x;
    const int wave = tid >> 6, lane = tid & 63, quad = lane >> 4, l16 = lane & 15;
    const int n0 = blockIdx.x * 64, m0 = blockIdx.y * 64;

    int arow = m0 + wave * 16 + l16;
    if (MODE == 3 && arow > PP - 1) arow = PP - 1;
    const ushort_t* Xp = X + (size_t)arow * 512 + quad * 8;
    const ushort_t* Wp = W + (size_t)(n0 + l16) * 512 + quad * 8;

    f32x4 acc[4];
    #pragma unroll
    for (int i = 0; i < 4; ++i) acc[i] = (f32x4){0.f, 0.f, 0.f, 0.f};

    #pragma unroll
    for (int k0 = 0; k0 < 512; k0 += 64) {
        short8 a0 = *(const short8*)(Xp + k0);
        short8 a1 = *(const short8*)(Xp + k0 + 32);
        #pragma unroll
        for (int ns = 0; ns < 4; ++ns) {
            short8 b0 = *(const short8*)(Wp + (size_t)ns * 16 * 512 + k0);
            short8 b1v = *(const short8*)(Wp + (size_t)ns * 16 * 512 + k0 + 32);
            acc[ns] = MFMA(a0, b0, acc[ns]);
            acc[ns] = MFMA(a1, b1v, acc[ns]);
        }
    }

    #pragma unroll
    for (int ns = 0; ns < 4; ++ns)
    #pragma unroll
    for (int r = 0; r < 4; ++r) {
        const int row = m0 + wave * 16 + quad * 4 + r;
        const int col = n0 + ns * 16 + l16;
        const float v = acc[ns][r];
        if (MODE == 0) {
            float base = v + b1[col];
            size_t idx = (((size_t)(row >> 10) * HH + (col >> 6)) * SS + (row & 1023)) * CC + (col & 63);
            Y1[idx] = f2bf(base + b2[col]);
            Y2[idx] = f2bf(base + b3[col]);
        } else if (MODE == 1) {
            size_t idx = (((size_t)(row >> 10) * HH + (col >> 6)) * SS + (row & 1023)) * CC + (col & 63);
            Y1[idx] = f2bf(v + b1[col]);
        } else if (MODE == 2) {
            // V^T layout: [bh][c][s]
            size_t idx = (((size_t)(row >> 10) * HH + (col >> 6)) * CC + (col & 63)) * SS + (row & 1023);
            Y1[idx] = f2bf(v + b1[col]);
        } else if (MODE == 3) {
            if (row < PP)
                Y1[((size_t)(col >> 6) * PP + row) * CC + (col & 63)] = f2bf(v);
        } else {
            Yf[(size_t)row * 512 + col] = v + b1[col];
        }
    }
}

// ---------------------------------------------------------------------------
// Fused rel-pos flash attention, barrier-free.
// grid (64 bh, 16 s-tiles): all s-tiles of a bh share an XCD (linear%8==h).
// All K/V^T/p MFMA B-fragments loaded directly from global (L2-resident).
// LDS: wave-private Bscr (fp32 band scratch) + Pscr (P relayout) only.
// ---------------------------------------------------------------------------
__global__ __launch_bounds__(256) void attn_kernel(
    const ushort_t* __restrict__ qu_g, const ushort_t* __restrict__ qv_g,
    const ushort_t* __restrict__ kb, const ushort_t* __restrict__ vt_g,
    const ushort_t* __restrict__ pbf, const unsigned char* __restrict__ mask,
    ushort_t* __restrict__ xg)
{
    const int bh = blockIdx.x;            // b*8 + h
    const int s0 = blockIdx.y * 64;
    const int b = bh >> 3, h = bh & 7;
    const int tid = threadIdx.x;
    const int wave = tid >> 6, lane = tid & 63, quad = lane >> 4, l16 = lane & 15;

    __shared__ __align__(16) float    Bscr[4][16][84];   // band scratch, fp32
    __shared__ __align__(16) ushort_t Pscr[4][16][72];   // P C/D->A relayout

    // Q fragments (A-operand, m = lane&15), loaded once
    const size_t qoff = ((size_t)bh * SS + s0 + wave * 16 + l16) * CC;
    short8 quA[2], qvA[2];
    quA[0] = *(const short8*)(qu_g + qoff + quad * 8);
    quA[1] = *(const short8*)(qu_g + qoff + 32 + quad * 8);
    qvA[0] = *(const short8*)(qv_g + qoff + quad * 8);
    qvA[1] = *(const short8*)(qv_g + qoff + 32 + quad * 8);

    f32x4 O[4];
    #pragma unroll
    for (int i = 0; i < 4; ++i) O[i] = (f32x4){0.f, 0.f, 0.f, 0.f};
    float mrow[4] = {-1e30f, -1e30f, -1e30f, -1e30f};
    float lrow[4] = {0.f, 0.f, 0.f, 0.f};

    const ushort_t* kbase  = kb   + ((size_t)bh << 10) * CC;   // [t][c]
    const ushort_t* vtbase = vt_g + ((size_t)bh << 6) * SS;    // [c][s]
    const ushort_t* pbase  = pbf  + (size_t)h * PP * CC;       // [u][c]
    const int uwbase = 1008 - s0 - wave * 16;  // +t0+us*16+l16 = global p row
    const unsigned char* mbase = mask + b * SS;

    for (int t0 = 0; t0 < SS; t0 += 64) {
        // ---- direct-from-global B fragments: K and p band ----
        short8 kf[4][2], pf[5][2];
        #pragma unroll
        for (int ns = 0; ns < 4; ++ns) {
            const ushort_t* kr = kbase + (size_t)(t0 + ns * 16 + l16) * CC + quad * 8;
            kf[ns][0] = *(const short8*)(kr);
            kf[ns][1] = *(const short8*)(kr + 32);
        }
        #pragma unroll
        for (int us = 0; us < 5; ++us) {
            int gu = uwbase + t0 + us * 16 + l16;
            if (gu > PP - 1) gu = PP - 1;
            const ushort_t* pr = pbase + (size_t)gu * CC + quad * 8;
            pf[us][0] = *(const short8*)(pr);
            pf[us][1] = *(const short8*)(pr + 32);
        }

        // ---- AC = q_u . K^T ----
        f32x4 ac[4];
        #pragma unroll
        for (int ns = 0; ns < 4; ++ns) {
            ac[ns] = (f32x4){0.f, 0.f, 0.f, 0.f};
            ac[ns] = MFMA(quA[0], kf[ns][0], ac[ns]);
            ac[ns] = MFMA(quA[1], kf[ns][1], ac[ns]);
        }
        // ---- band = q_v . p_band^T (wave-local 16 x 80) ----
        #pragma unroll
        for (int us = 0; us < 5; ++us) {
            f32x4 bd = (f32x4){0.f, 0.f, 0.f, 0.f};
            bd = MFMA(qvA[0], pf[us][0], bd);
            bd = MFMA(qvA[1], pf[us][1], bd);
            #pragma unroll
            for (int r = 0; r < 4; ++r)
                Bscr[wave][quad * 4 + r][us * 16 + l16] = bd[r];
        }

        // ---- shift-gather + scale + mask ----
        float pv[4][4];
        #pragma unroll
        for (int ns = 0; ns < 4; ++ns) {
            const bool mk = mbase[t0 + ns * 16 + l16] != 0;
            #pragma unroll
            for (int r = 0; r < 4; ++r) {
                const int sl = quad * 4 + r;
                float bdv = Bscr[wave][sl][ns * 16 + l16 + 15 - sl];
                float scv = (ac[ns][r] + bdv) * 0.125f;
                pv[ns][r] = mk ? -1e30f : scv;
            }
        }
        // ---- online softmax (rows live in quads: 16 lanes per row) ----
        #pragma unroll
        for (int r = 0; r < 4; ++r) {
            float mx = fmaxf(fmaxf(pv[0][r], pv[1][r]), fmaxf(pv[2][r], pv[3][r]));
            mx = fmaxf(mx, __shfl_xor(mx, 1));
            mx = fmaxf(mx, __shfl_xor(mx, 2));
            mx = fmaxf(mx, __shfl_xor(mx, 4));
            mx = fmaxf(mx, __shfl_xor(mx, 8));
            const float mnew = fmaxf(mrow[r], mx);
            const float alpha = __expf(mrow[r] - mnew);
            mrow[r] = mnew;
            float s = 0.f;
            #pragma unroll
            for (int ns = 0; ns < 4; ++ns) {
                float p = __expf(pv[ns][r] - mnew);
                pv[ns][r] = p; s += p;
            }
            s += __shfl_xor(s, 1); s += __shfl_xor(s, 2);
            s += __shfl_xor(s, 4); s += __shfl_xor(s, 8);
            lrow[r] = lrow[r] * alpha + s;
            #pragma unroll
            for (int ns = 0; ns < 4; ++ns) O[ns][r] *= alpha;
        }
        // ---- P: C/D layout -> A layout via wave-private LDS ----
        #pragma unroll
        for (int ns = 0; ns < 4; ++ns)
            #pragma unroll
            for (int r = 0; r < 4; ++r)
                Pscr[wave][quad * 4 + r][ns * 16 + l16] = f2bf(pv[ns][r]);
        short8 pA0 = *(const short8*)&Pscr[wave][l16][quad * 8];
        short8 pA1 = *(const short8*)&Pscr[wave][l16][32 + quad * 8];
        // ---- O += P . V  (V^T fragments direct from global) ----
        #pragma unroll
        for (int ns = 0; ns < 4; ++ns) {
            const ushort_t* vr = vtbase + (size_t)(ns * 16 + l16) * SS + t0 + quad * 8;
            short8 v0 = *(const short8*)(vr);
            short8 v1 = *(const short8*)(vr + 32);
            O[ns] = MFMA(pA0, v0, O[ns]);
            O[ns] = MFMA(pA1, v1, O[ns]);
        }
    }

    // ---- finalize: O /= l, write x bf16 [B,S,D] ----
    #pragma unroll
    for (int r = 0; r < 4; ++r) {
        const float inv = 1.0f / lrow[r];
        const int s = s0 + wave * 16 + quad * 4 + r;
        #pragma unroll
        for (int ns = 0; ns < 4; ++ns) {
            const int c = ns * 16 + l16;
            xg[((size_t)b * SS + s) * DD + h * CC + c] = f2bf(O[ns][r] * inv);
        }
    }
}

// ---------------------------------------------------------------------------
extern "C" void kernel_launch(void* const* d_in, const int* in_sizes, int n_in,
                              void* d_out, int out_size, void* d_ws, size_t ws_size,
                              hipStream_t stream)
{
    (void)in_sizes; (void)n_in; (void)out_size; (void)ws_size;

    const float* query = (const float*)d_in[0];
    const float* key_  = (const float*)d_in[1];
    const float* value = (const float*)d_in[2];
    const float* pos   = (const float*)d_in[3];
    const unsigned char* mask = (const unsigned char*)d_in[4];
    const float* Wq   = (const float*)d_in[5];
    const float* bq   = (const float*)d_in[6];
    const float* Wk   = (const float*)d_in[7];
    const float* bk   = (const float*)d_in[8];
    const float* Wv   = (const float*)d_in[9];
    const float* bv   = (const float*)d_in[10];
    const float* Wpos = (const float*)d_in[11];
    const float* Wout = (const float*)d_in[12];
    const float* bout = (const float*)d_in[13];
    const float* ub   = (const float*)d_in[14];
    const float* vb   = (const float*)d_in[15];

    const size_t NBS = (size_t)BB * SS * DD;   // 4194304
    const size_t NP  = (size_t)PP * DD;        // 1048064 (== H*P*C)
    const size_t NW  = (size_t)DD * DD;        // 262144

    ushort_t* xq   = (ushort_t*)d_ws;
    ushort_t* xk   = xq + NBS;
    ushort_t* xv   = xk + NBS;
    ushort_t* xpos = xv + NBS;
    ushort_t* wt   = xpos + NP;                // 5 transposed weights
    ushort_t* qu   = wt + 5 * NW;
    ushort_t* qv   = qu + NBS;
    ushort_t* kbuf = qv + NBS;
    ushort_t* vtb  = kbuf + NBS;               // V^T [bh][c][s]
    ushort_t* pbuf = vtb + NBS;                // NP elems
    ushort_t* xg   = pbuf + NP;

    ushort_t* WtQ = wt;
    ushort_t* WtK = wt + NW;
    ushort_t* WtV = wt + 2 * NW;
    ushort_t* WtP = wt + 3 * NW;
    ushort_t* WtO = wt + 4 * NW;

    dim3 blk(256);

    cast_kernel<<<dim3(3648), blk, 0, stream>>>(
        query, key_, value, pos, Wq, Wk, Wv, Wpos, Wout,
        xq, xk, xv, xpos, wt);

    proj_kernel<0><<<dim3(8, 128), blk, 0, stream>>>(xq, WtQ, bq, ub, vb, qu, qv, nullptr);
    proj_kernel<1><<<dim3(8, 128), blk, 0, stream>>>(xk, WtK, bk, nullptr, nullptr, kbuf, nullptr, nullptr);
    proj_kernel<2><<<dim3(8, 128), blk, 0, stream>>>(xv, WtV, bv, nullptr, nullptr, vtb, nullptr, nullptr);
    proj_kernel<3><<<dim3(8, 32), blk, 0, stream>>>(xpos, WtP, nullptr, nullptr, nullptr, pbuf, nullptr, nullptr);

    attn_kernel<<<dim3(64, 16), blk, 0, stream>>>(qu, qv, kbuf, vtb, pbuf, mask, xg);

    proj_kernel<4><<<dim3(8, 128), blk, 0, stream>>>(xg, WtO, bout, nullptr, nullptr, nullptr, nullptr, (float*)d_out);
}

// Round 4
// 322.447 us; speedup vs baseline: 1.5546x; 1.5546x over previous
//
#include <hip/hip_runtime.h>
#include <math.h>

typedef unsigned short ushort_t;
typedef __attribute__((ext_vector_type(8))) short short8;
typedef __attribute__((ext_vector_type(4))) float f32x4;

#define MFMA(a,b,c) __builtin_amdgcn_mfma_f32_16x16x32_bf16((a),(b),(c),0,0,0)

// Problem constants
#define BB 8
#define SS 1024
#define DD 512
#define HH 8
#define CC 64
#define PP 2047   // 2S-1

static __device__ __forceinline__ ushort_t f2bf(float f) {
    unsigned u = __float_as_uint(f);
    u += 0x7fffu + ((u >> 16) & 1u);       // RNE
    return (ushort_t)(u >> 16);
}
static __device__ __forceinline__ unsigned pack2(float a, float b) {
    return (unsigned)f2bf(a) | ((unsigned)f2bf(b) << 16);
}

// ---------------------------------------------------------------------------
// Weight transpose+cast: W[k][n] fp32 -> Wt[n][k] bf16, 5 weights.
// grid 320 blocks: wi = bid>>6, 64 tiles of 64x64 each.
// ---------------------------------------------------------------------------
__global__ __launch_bounds__(256) void wtrans_kernel(
    const float* __restrict__ Wq, const float* __restrict__ Wk,
    const float* __restrict__ Wv, const float* __restrict__ Wp,
    const float* __restrict__ Wo, ushort_t* __restrict__ wt)
{
    __shared__ float T[64][65];
    const int bid = blockIdx.x, tid = threadIdx.x;
    const int wi   = bid >> 6;
    const int tile = bid & 63;
    const float* Wsrc = (wi == 0) ? Wq : (wi == 1) ? Wk : (wi == 2) ? Wv
                      : (wi == 3) ? Wp : Wo;
    ushort_t* Wdst = wt + (size_t)wi * 262144;
    const int tk0 = (tile >> 3) * 64, tn0 = (tile & 7) * 64;
    const int r = tid >> 2, c4 = (tid & 3) * 16;
    #pragma unroll
    for (int rep = 0; rep < 4; ++rep) {
        float4 f = *(const float4*)(Wsrc + (size_t)(tk0 + r) * 512 + tn0 + c4 + rep * 4);
        T[r][c4 + rep * 4 + 0] = f.x; T[r][c4 + rep * 4 + 1] = f.y;
        T[r][c4 + rep * 4 + 2] = f.z; T[r][c4 + rep * 4 + 3] = f.w;
    }
    __syncthreads();
    #pragma unroll
    for (int rep = 0; rep < 4; ++rep) {
        uint2 u;
        u.x = pack2(T[c4 + rep * 4 + 0][r], T[c4 + rep * 4 + 1][r]);
        u.y = pack2(T[c4 + rep * 4 + 2][r], T[c4 + rep * 4 + 3][r]);
        *(uint2*)(Wdst + (size_t)(tn0 + r) * 512 + tk0 + c4 + rep * 4) = u;
    }
}

// ---------------------------------------------------------------------------
// MFMA projection GEMM, 128x128 tile, 4 waves (each 64x64 = 4x4 frags), BK=64.
// Cast fp32->bf16 fused into LDS staging (SRC=0) or bf16 passthrough (SRC=1).
// MODE 0: Q -> qu,qv [B,H,S,C];  1: K -> [B,H,S,C];  2: V -> V^T [BH,C,S]
// MODE 3: pos (M=2047) -> [H,P,C];  4: out-proj -> fp32 row-major
// ---------------------------------------------------------------------------
template<int MODE, int SRC>
__global__ __launch_bounds__(256) void proj_kernel(
    const void* __restrict__ Xv, const ushort_t* __restrict__ W,
    const float* __restrict__ b1, const float* __restrict__ b2,
    const float* __restrict__ b3,
    ushort_t* __restrict__ Y1, ushort_t* __restrict__ Y2,
    float* __restrict__ Yf)
{
    __shared__ __align__(16) ushort_t Xs[128][72];
    __shared__ __align__(16) ushort_t Ws[128][72];
    const int tid = threadIdx.x;
    const int wave = tid >> 6, lane = tid & 63, quad = lane >> 4, l16 = lane & 15;
    const int n0 = blockIdx.x * 128, m0 = blockIdx.y * 128;
    const int mb = (wave >> 1) * 64, nb = (wave & 1) * 64;

    f32x4 acc[4][4];
    #pragma unroll
    for (int i = 0; i < 4; ++i)
        #pragma unroll
        for (int j = 0; j < 4; ++j) acc[i][j] = (f32x4){0.f, 0.f, 0.f, 0.f};

    for (int k0 = 0; k0 < 512; k0 += 64) {
        #pragma unroll
        for (int i = 0; i < 4; ++i) {
            int u = tid + 256 * i; int r = u >> 3; int c8 = (u & 7) * 8;
            int row = m0 + r;
            if (MODE == 3 && row > PP - 1) row = PP - 1;
            if (SRC == 0) {
                const float* xp = (const float*)Xv + (size_t)row * 512 + k0 + c8;
                float4 fa = *(const float4*)xp;
                float4 fb = *(const float4*)(xp + 4);
                uint4 pk;
                pk.x = pack2(fa.x, fa.y); pk.y = pack2(fa.z, fa.w);
                pk.z = pack2(fb.x, fb.y); pk.w = pack2(fb.z, fb.w);
                *(uint4*)&Xs[r][c8] = pk;
            } else {
                *(uint4*)&Xs[r][c8] =
                    *(const uint4*)((const ushort_t*)Xv + (size_t)row * 512 + k0 + c8);
            }
            *(uint4*)&Ws[r][c8] = *(const uint4*)(W + (size_t)(n0 + r) * 512 + k0 + c8);
        }
        __syncthreads();
        #pragma unroll
        for (int kk = 0; kk < 2; ++kk) {
            short8 av[4], bv[4];
            #pragma unroll
            for (int ms = 0; ms < 4; ++ms)
                av[ms] = *(const short8*)&Xs[mb + ms * 16 + l16][kk * 32 + quad * 8];
            #pragma unroll
            for (int ns = 0; ns < 4; ++ns)
                bv[ns] = *(const short8*)&Ws[nb + ns * 16 + l16][kk * 32 + quad * 8];
            #pragma unroll
            for (int ms = 0; ms < 4; ++ms)
                #pragma unroll
                for (int ns = 0; ns < 4; ++ns)
                    acc[ms][ns] = MFMA(av[ms], bv[ns], acc[ms][ns]);
        }
        __syncthreads();
    }

    #pragma unroll
    for (int ms = 0; ms < 4; ++ms)
    #pragma unroll
    for (int ns = 0; ns < 4; ++ns)
    #pragma unroll
    for (int r = 0; r < 4; ++r) {
        const int row = m0 + mb + ms * 16 + quad * 4 + r;
        const int col = n0 + nb + ns * 16 + l16;
        const float v = acc[ms][ns][r];
        if (MODE == 0) {
            float base = v + b1[col];
            size_t idx = (((size_t)(row >> 10) * HH + (col >> 6)) * SS + (row & 1023)) * CC + (col & 63);
            Y1[idx] = f2bf(base + b2[col]);
            Y2[idx] = f2bf(base + b3[col]);
        } else if (MODE == 1) {
            size_t idx = (((size_t)(row >> 10) * HH + (col >> 6)) * SS + (row & 1023)) * CC + (col & 63);
            Y1[idx] = f2bf(v + b1[col]);
        } else if (MODE == 2) {
            size_t idx = (((size_t)(row >> 10) * HH + (col >> 6)) * CC + (col & 63)) * SS + (row & 1023);
            Y1[idx] = f2bf(v + b1[col]);
        } else if (MODE == 3) {
            if (row < PP)
                Y1[((size_t)(col >> 6) * PP + row) * CC + (col & 63)] = f2bf(v);
        } else {
            Yf[(size_t)row * 512 + col] = v + b1[col];
        }
    }
}

// ---------------------------------------------------------------------------
// Fused rel-pos flash attention.
// Block = (bh, 64 s-rows), 4 waves (wave owns 16 s-rows). 16 t-tiles of 64.
// LDS-staged K / V^T / rolling 128-row p-band, prefetched to VGPR each iter.
// Fixed-max softmax (p = exp(s-40), normalize at end — no per-iter reductions).
// rel-shift via in-wave shuffles of the band MFMA output.
// ---------------------------------------------------------------------------
__global__ __launch_bounds__(256) void attn_kernel(
    const ushort_t* __restrict__ qu_g, const ushort_t* __restrict__ qv_g,
    const ushort_t* __restrict__ kb, const ushort_t* __restrict__ vt_g,
    const ushort_t* __restrict__ pbf, const unsigned char* __restrict__ mask,
    ushort_t* __restrict__ xg)
{
    const int bh = blockIdx.x;            // b*8 + h
    const int s0 = blockIdx.y * 64;
    const int b = bh >> 3, h = bh & 7;
    const int tid = threadIdx.x;
    const int wave = tid >> 6, lane = tid & 63, quad = lane >> 4, l16 = lane & 15;

    __shared__ __align__(16) ushort_t Ks[64][72];
    __shared__ __align__(16) ushort_t Vts[64][72];
    __shared__ __align__(16) ushort_t Pb[128][72];
    __shared__ __align__(16) ushort_t Pscr[4][16][72];

    // Q fragments (A-operand, m = lane&15), loaded once
    const size_t qoff = ((size_t)bh * SS + s0 + wave * 16 + l16) * CC;
    short8 quA[2], qvA[2];
    quA[0] = *(const short8*)(qu_g + qoff + quad * 8);
    quA[1] = *(const short8*)(qu_g + qoff + 32 + quad * 8);
    qvA[0] = *(const short8*)(qv_g + qoff + quad * 8);
    qvA[1] = *(const short8*)(qv_g + qoff + 32 + quad * 8);

    f32x4 O[4];
    #pragma unroll
    for (int i = 0; i < 4; ++i) O[i] = (f32x4){0.f, 0.f, 0.f, 0.f};
    float lsum[4] = {0.f, 0.f, 0.f, 0.f};

    const ushort_t* kbase  = kb   + ((size_t)bh << 10) * CC;   // [t][c]
    const ushort_t* vtbase = vt_g + ((size_t)bh << 6) * SS;    // [c][s]
    const ushort_t* pbase  = pbf  + (size_t)h * PP * CC;       // [u][c]
    const unsigned char* mbase = mask + b * SS;

    const int R0base = 960 - s0;              // band start row at t0: R0base+t0
    const int uwread = 1008 - s0 - wave * 16; // +t0+us*16+l16 = global p row

    // ---- initial staging: K(t0=0), Vt(t0=0), full 128-row p band ----
    {
        uint4 kp[2], vp[2], pp[4];
        #pragma unroll
        for (int i = 0; i < 2; ++i) {
            int u = tid + 256 * i; int r = u >> 3; int cc = (u & 7) * 8;
            kp[i] = *(const uint4*)(kbase + (size_t)r * CC + cc);
            vp[i] = *(const uint4*)(vtbase + (size_t)r * SS + cc);
        }
        #pragma unroll
        for (int i = 0; i < 4; ++i) {
            int u = tid + 256 * i; int r = u >> 3; int cc = (u & 7) * 8;
            int g = R0base + r; if (g > PP - 1) g = PP - 1;
            pp[i] = *(const uint4*)(pbase + (size_t)g * CC + cc);
        }
        #pragma unroll
        for (int i = 0; i < 2; ++i) {
            int u = tid + 256 * i; int r = u >> 3; int cc = (u & 7) * 8;
            *(uint4*)&Ks[r][cc]  = kp[i];
            *(uint4*)&Vts[r][cc] = vp[i];
        }
        #pragma unroll
        for (int i = 0; i < 4; ++i) {
            int u = tid + 256 * i; int r = u >> 3; int cc = (u & 7) * 8;
            *(uint4*)&Pb[(R0base + r) & 127][cc] = pp[i];
        }
    }
    __syncthreads();

    for (int t0 = 0; t0 < SS; t0 += 64) {
        const bool more = (t0 + 64) < SS;
        // ---- prefetch next tile to VGPRs ----
        uint4 kp[2], vp[2], pp[2];
        if (more) {
            #pragma unroll
            for (int i = 0; i < 2; ++i) {
                int u = tid + 256 * i; int r = u >> 3; int cc = (u & 7) * 8;
                kp[i] = *(const uint4*)(kbase + (size_t)(t0 + 64 + r) * CC + cc);
                vp[i] = *(const uint4*)(vtbase + (size_t)r * SS + t0 + 64 + cc);
                int g = R0base + t0 + 128 + r; if (g > PP - 1) g = PP - 1;
                pp[i] = *(const uint4*)(pbase + (size_t)g * CC + cc);
            }
        }

        // ---- AC = q_u . K^T ----
        f32x4 ac[4];
        #pragma unroll
        for (int ns = 0; ns < 4; ++ns) {
            ac[ns] = (f32x4){0.f, 0.f, 0.f, 0.f};
            #pragma unroll
            for (int kk = 0; kk < 2; ++kk) {
                short8 kf = *(const short8*)&Ks[ns * 16 + l16][kk * 32 + quad * 8];
                ac[ns] = MFMA(quA[kk], kf, ac[ns]);
            }
        }
        // ---- band = q_v . p_band^T (wave-local 16 x 80) ----
        f32x4 bd[5];
        #pragma unroll
        for (int us = 0; us < 5; ++us) {
            bd[us] = (f32x4){0.f, 0.f, 0.f, 0.f};
            #pragma unroll
            for (int kk = 0; kk < 2; ++kk) {
                short8 pf = *(const short8*)&Pb[(uwread + t0 + us * 16 + l16) & 127][kk * 32 + quad * 8];
                bd[us] = MFMA(qvA[kk], pf, bd[us]);
            }
        }

        // ---- shift (in-wave shuffle) + exp(s - 40) + mask; accumulate lsum ----
        bool mk[4];
        #pragma unroll
        for (int ns = 0; ns < 4; ++ns) mk[ns] = mbase[t0 + ns * 16 + l16] != 0;

        float pvv[4][4];
        #pragma unroll
        for (int r = 0; r < 4; ++r) {
            const int sl = quad * 4 + r;
            const int d = l16 + 15 - sl;
            const int srcl = quad * 16 + (d & 15);
            const bool use_hi = d >= 16;
            #pragma unroll
            for (int ns = 0; ns < 4; ++ns) {
                float lo = __shfl(bd[ns][r], srcl, 64);
                float hi = __shfl(bd[ns + 1][r], srcl, 64);
                float bdv = use_hi ? hi : lo;
                float p = __expf((ac[ns][r] + bdv) * 0.125f - 40.f);
                p = mk[ns] ? 0.f : p;
                pvv[ns][r] = p;
                lsum[r] += p;
            }
        }

        // ---- P: C/D layout -> A layout via wave-private LDS ----
        #pragma unroll
        for (int ns = 0; ns < 4; ++ns)
            #pragma unroll
            for (int r = 0; r < 4; ++r)
                Pscr[wave][quad * 4 + r][ns * 16 + l16] = f2bf(pvv[ns][r]);
        short8 pA0 = *(const short8*)&Pscr[wave][l16][quad * 8];
        short8 pA1 = *(const short8*)&Pscr[wave][l16][32 + quad * 8];

        // ---- O += P . V ----
        #pragma unroll
        for (int ns = 0; ns < 4; ++ns) {
            short8 v0 = *(const short8*)&Vts[ns * 16 + l16][quad * 8];
            short8 v1 = *(const short8*)&Vts[ns * 16 + l16][32 + quad * 8];
            O[ns] = MFMA(pA0, v0, O[ns]);
            O[ns] = MFMA(pA1, v1, O[ns]);
        }

        if (more) {
            __syncthreads();   // all waves done reading Ks/Vts/Pb
            #pragma unroll
            for (int i = 0; i < 2; ++i) {
                int u = tid + 256 * i; int r = u >> 3; int cc = (u & 7) * 8;
                *(uint4*)&Ks[r][cc]  = kp[i];
                *(uint4*)&Vts[r][cc] = vp[i];
                *(uint4*)&Pb[(R0base + t0 + 128 + r) & 127][cc] = pp[i];
            }
            __syncthreads();
        }
    }

    // ---- finalize: reduce lsum over 16 lanes, O /= l, write bf16 [B,S,D] ----
    #pragma unroll
    for (int r = 0; r < 4; ++r) {
        float s = lsum[r];
        s += __shfl_xor(s, 1, 64); s += __shfl_xor(s, 2, 64);
        s += __shfl_xor(s, 4, 64); s += __shfl_xor(s, 8, 64);
        const float inv = 1.0f / s;
        const int srow = s0 + wave * 16 + quad * 4 + r;
        #pragma unroll
        for (int ns = 0; ns < 4; ++ns) {
            const int c = ns * 16 + l16;
            xg[((size_t)b * SS + srow) * DD + h * CC + c] = f2bf(O[ns][r] * inv);
        }
    }
}

// ---------------------------------------------------------------------------
extern "C" void kernel_launch(void* const* d_in, const int* in_sizes, int n_in,
                              void* d_out, int out_size, void* d_ws, size_t ws_size,
                              hipStream_t stream)
{
    (void)in_sizes; (void)n_in; (void)out_size; (void)ws_size;

    const float* query = (const float*)d_in[0];
    const float* key_  = (const float*)d_in[1];
    const float* value = (const float*)d_in[2];
    const float* pos   = (const float*)d_in[3];
    const unsigned char* mask = (const unsigned char*)d_in[4];
    const float* Wq   = (const float*)d_in[5];
    const float* bq   = (const float*)d_in[6];
    const float* Wk   = (const float*)d_in[7];
    const float* bk   = (const float*)d_in[8];
    const float* Wv   = (const float*)d_in[9];
    const float* bv   = (const float*)d_in[10];
    const float* Wpos = (const float*)d_in[11];
    const float* Wout = (const float*)d_in[12];
    const float* bout = (const float*)d_in[13];
    const float* ub   = (const float*)d_in[14];
    const float* vb   = (const float*)d_in[15];

    const size_t NBS = (size_t)BB * SS * DD;   // 4194304
    const size_t NP  = (size_t)PP * DD;        // 1048064
    const size_t NW  = (size_t)DD * DD;        // 262144

    ushort_t* wt   = (ushort_t*)d_ws;          // 5 transposed weights
    ushort_t* qu   = wt + 5 * NW;
    ushort_t* qv   = qu + NBS;
    ushort_t* kbuf = qv + NBS;
    ushort_t* vtb  = kbuf + NBS;               // V^T [bh][c][s]
    ushort_t* pbuf = vtb + NBS;                // [h][u][c]
    ushort_t* xg   = pbuf + NP;

    ushort_t* WtQ = wt;
    ushort_t* WtK = wt + NW;
    ushort_t* WtV = wt + 2 * NW;
    ushort_t* WtP = wt + 3 * NW;
    ushort_t* WtO = wt + 4 * NW;

    dim3 blk(256);

    wtrans_kernel<<<dim3(320), blk, 0, stream>>>(Wq, Wk, Wv, Wpos, Wout, wt);

    proj_kernel<0, 0><<<dim3(4, 64), blk, 0, stream>>>(query, WtQ, bq, ub, vb, qu, qv, nullptr);
    proj_kernel<1, 0><<<dim3(4, 64), blk, 0, stream>>>(key_, WtK, bk, nullptr, nullptr, kbuf, nullptr, nullptr);
    proj_kernel<2, 0><<<dim3(4, 64), blk, 0, stream>>>(value, WtV, bv, nullptr, nullptr, vtb, nullptr, nullptr);
    proj_kernel<3, 0><<<dim3(4, 16), blk, 0, stream>>>(pos, WtP, nullptr, nullptr, nullptr, pbuf, nullptr, nullptr);

    attn_kernel<<<dim3(64, 16), blk, 0, stream>>>(qu, qv, kbuf, vtb, pbuf, mask, xg);

    proj_kernel<4, 1><<<dim3(4, 64), blk, 0, stream>>>(xg, WtO, bout, nullptr, nullptr, nullptr, nullptr, (float*)d_out);
}

// Round 5
// 247.663 us; speedup vs baseline: 2.0241x; 1.3020x over previous
//
#include <hip/hip_runtime.h>
#include <math.h>

typedef unsigned short ushort_t;
typedef __attribute__((ext_vector_type(8))) short short8;
typedef __attribute__((ext_vector_type(4))) float f32x4;

#define MFMA(a,b,c) __builtin_amdgcn_mfma_f32_16x16x32_bf16((a),(b),(c),0,0,0)

// Problem constants
#define BB 8
#define SS 1024
#define DD 512
#define HH 8
#define CC 64
#define PP 2047   // 2S-1

static __device__ __forceinline__ ushort_t f2bf(float f) {
    unsigned u = __float_as_uint(f);
    u += 0x7fffu + ((u >> 16) & 1u);       // RNE
    return (ushort_t)(u >> 16);
}
static __device__ __forceinline__ unsigned pack2(float a, float b) {
    return (unsigned)f2bf(a) | ((unsigned)f2bf(b) << 16);
}

// ---------------------------------------------------------------------------
// Weight transpose+cast: W[k][n] fp32 -> Wt[n][k] bf16, 5 weights.
// ---------------------------------------------------------------------------
__global__ __launch_bounds__(256) void wtrans_kernel(
    const float* __restrict__ Wq, const float* __restrict__ Wk,
    const float* __restrict__ Wv, const float* __restrict__ Wp,
    const float* __restrict__ Wo, ushort_t* __restrict__ wt)
{
    __shared__ float T[64][65];
    const int bid = blockIdx.x, tid = threadIdx.x;
    const int wi   = bid >> 6;
    const int tile = bid & 63;
    const float* Wsrc = (wi == 0) ? Wq : (wi == 1) ? Wk : (wi == 2) ? Wv
                      : (wi == 3) ? Wp : Wo;
    ushort_t* Wdst = wt + (size_t)wi * 262144;
    const int tk0 = (tile >> 3) * 64, tn0 = (tile & 7) * 64;
    const int r = tid >> 2, c4 = (tid & 3) * 16;
    #pragma unroll
    for (int rep = 0; rep < 4; ++rep) {
        float4 f = *(const float4*)(Wsrc + (size_t)(tk0 + r) * 512 + tn0 + c4 + rep * 4);
        T[r][c4 + rep * 4 + 0] = f.x; T[r][c4 + rep * 4 + 1] = f.y;
        T[r][c4 + rep * 4 + 2] = f.z; T[r][c4 + rep * 4 + 3] = f.w;
    }
    __syncthreads();
    #pragma unroll
    for (int rep = 0; rep < 4; ++rep) {
        uint2 u;
        u.x = pack2(T[c4 + rep * 4 + 0][r], T[c4 + rep * 4 + 1][r]);
        u.y = pack2(T[c4 + rep * 4 + 2][r], T[c4 + rep * 4 + 3][r]);
        *(uint2*)(Wdst + (size_t)(tn0 + r) * 512 + tk0 + c4 + rep * 4) = u;
    }
}

// ---------------------------------------------------------------------------
// Fused Q/K/V/pos projection: one launch, 832 blocks (3.25/CU co-resident).
// 128x128 tile, 4 waves, BK=64, fp32->bf16 cast fused into staging.
// bid&3 = n-tile; bid>>2 = m-tile: [0,64) Q, [64,128) K, [128,192) V,
// [192,208) pos.
// ---------------------------------------------------------------------------
__global__ __launch_bounds__(256) void qkvpos_kernel(
    const float* __restrict__ Xq, const float* __restrict__ Xk,
    const float* __restrict__ Xv, const float* __restrict__ Xp,
    const ushort_t* __restrict__ wt,
    const float* __restrict__ bq, const float* __restrict__ bk,
    const float* __restrict__ bv,
    const float* __restrict__ ub, const float* __restrict__ vbias,
    ushort_t* __restrict__ qu, ushort_t* __restrict__ qvo,
    ushort_t* __restrict__ kbuf, ushort_t* __restrict__ vtb,
    ushort_t* __restrict__ pbuf)
{
    __shared__ __align__(16) ushort_t Xs[128][72];
    __shared__ __align__(16) ushort_t Ws[128][72];
    const int tid = threadIdx.x;
    const int wave = tid >> 6, lane = tid & 63, quad = lane >> 4, l16 = lane & 15;
    const int bid = blockIdx.x;
    const int n0 = (bid & 3) * 128;
    const int mt = bid >> 2;
    int mode, mtl;
    if (mt < 64)       { mode = 0; mtl = mt; }
    else if (mt < 128) { mode = 1; mtl = mt - 64; }
    else if (mt < 192) { mode = 2; mtl = mt - 128; }
    else               { mode = 3; mtl = mt - 192; }
    const int m0 = mtl * 128;
    const float* X = (mode == 0) ? Xq : (mode == 1) ? Xk : (mode == 2) ? Xv : Xp;
    const ushort_t* W = wt + (size_t)mode * 262144;
    const int mb = (wave >> 1) * 64, nb = (wave & 1) * 64;

    f32x4 acc[4][4];
    #pragma unroll
    for (int i = 0; i < 4; ++i)
        #pragma unroll
        for (int j = 0; j < 4; ++j) acc[i][j] = (f32x4){0.f, 0.f, 0.f, 0.f};

    for (int k0 = 0; k0 < 512; k0 += 64) {
        #pragma unroll
        for (int i = 0; i < 4; ++i) {
            int u = tid + 256 * i; int r = u >> 3; int c8 = (u & 7) * 8;
            int row = m0 + r;
            if (mode == 3 && row > PP - 1) row = PP - 1;
            const float* xp = X + (size_t)row * 512 + k0 + c8;
            float4 fa = *(const float4*)xp;
            float4 fb = *(const float4*)(xp + 4);
            uint4 pk;
            pk.x = pack2(fa.x, fa.y); pk.y = pack2(fa.z, fa.w);
            pk.z = pack2(fb.x, fb.y); pk.w = pack2(fb.z, fb.w);
            *(uint4*)&Xs[r][c8] = pk;
            *(uint4*)&Ws[r][c8] = *(const uint4*)(W + (size_t)(n0 + r) * 512 + k0 + c8);
        }
        __syncthreads();
        #pragma unroll
        for (int kk = 0; kk < 2; ++kk) {
            short8 av[4], bv4[4];
            #pragma unroll
            for (int ms = 0; ms < 4; ++ms)
                av[ms] = *(const short8*)&Xs[mb + ms * 16 + l16][kk * 32 + quad * 8];
            #pragma unroll
            for (int ns = 0; ns < 4; ++ns)
                bv4[ns] = *(const short8*)&Ws[nb + ns * 16 + l16][kk * 32 + quad * 8];
            #pragma unroll
            for (int ms = 0; ms < 4; ++ms)
                #pragma unroll
                for (int ns = 0; ns < 4; ++ns)
                    acc[ms][ns] = MFMA(av[ms], bv4[ns], acc[ms][ns]);
        }
        __syncthreads();
    }

    #pragma unroll
    for (int ms = 0; ms < 4; ++ms)
    #pragma unroll
    for (int ns = 0; ns < 4; ++ns)
    #pragma unroll
    for (int r = 0; r < 4; ++r) {
        const int row = m0 + mb + ms * 16 + quad * 4 + r;
        const int col = n0 + nb + ns * 16 + l16;
        const float v = acc[ms][ns][r];
        if (mode == 0) {
            float base = v + bq[col];
            size_t idx = (((size_t)(row >> 10) * HH + (col >> 6)) * SS + (row & 1023)) * CC + (col & 63);
            qu[idx]  = f2bf(base + ub[col]);
            qvo[idx] = f2bf(base + vbias[col]);
        } else if (mode == 1) {
            size_t idx = (((size_t)(row >> 10) * HH + (col >> 6)) * SS + (row & 1023)) * CC + (col & 63);
            kbuf[idx] = f2bf(v + bk[col]);
        } else if (mode == 2) {
            size_t idx = (((size_t)(row >> 10) * HH + (col >> 6)) * CC + (col & 63)) * SS + (row & 1023);
            vtb[idx] = f2bf(v + bv[col]);
        } else {
            if (row < PP)
                pbuf[((size_t)(col >> 6) * PP + row) * CC + (col & 63)] = f2bf(v);
        }
    }
}

// ---------------------------------------------------------------------------
// Out-projection: bf16 X @ WtO^T + bout -> fp32. 128x128 tile, 4 waves.
// ---------------------------------------------------------------------------
__global__ __launch_bounds__(256) void outproj_kernel(
    const ushort_t* __restrict__ X, const ushort_t* __restrict__ W,
    const float* __restrict__ b1, float* __restrict__ Yf)
{
    __shared__ __align__(16) ushort_t Xs[128][72];
    __shared__ __align__(16) ushort_t Ws[128][72];
    const int tid = threadIdx.x;
    const int wave = tid >> 6, lane = tid & 63, quad = lane >> 4, l16 = lane & 15;
    const int n0 = blockIdx.x * 128, m0 = blockIdx.y * 128;
    const int mb = (wave >> 1) * 64, nb = (wave & 1) * 64;

    f32x4 acc[4][4];
    #pragma unroll
    for (int i = 0; i < 4; ++i)
        #pragma unroll
        for (int j = 0; j < 4; ++j) acc[i][j] = (f32x4){0.f, 0.f, 0.f, 0.f};

    for (int k0 = 0; k0 < 512; k0 += 64) {
        #pragma unroll
        for (int i = 0; i < 4; ++i) {
            int u = tid + 256 * i; int r = u >> 3; int c8 = (u & 7) * 8;
            *(uint4*)&Xs[r][c8] = *(const uint4*)(X + (size_t)(m0 + r) * 512 + k0 + c8);
            *(uint4*)&Ws[r][c8] = *(const uint4*)(W + (size_t)(n0 + r) * 512 + k0 + c8);
        }
        __syncthreads();
        #pragma unroll
        for (int kk = 0; kk < 2; ++kk) {
            short8 av[4], bv4[4];
            #pragma unroll
            for (int ms = 0; ms < 4; ++ms)
                av[ms] = *(const short8*)&Xs[mb + ms * 16 + l16][kk * 32 + quad * 8];
            #pragma unroll
            for (int ns = 0; ns < 4; ++ns)
                bv4[ns] = *(const short8*)&Ws[nb + ns * 16 + l16][kk * 32 + quad * 8];
            #pragma unroll
            for (int ms = 0; ms < 4; ++ms)
                #pragma unroll
                for (int ns = 0; ns < 4; ++ns)
                    acc[ms][ns] = MFMA(av[ms], bv4[ns], acc[ms][ns]);
        }
        __syncthreads();
    }

    #pragma unroll
    for (int ms = 0; ms < 4; ++ms)
    #pragma unroll
    for (int ns = 0; ns < 4; ++ns)
    #pragma unroll
    for (int r = 0; r < 4; ++r) {
        const int row = m0 + mb + ms * 16 + quad * 4 + r;
        const int col = n0 + nb + ns * 16 + l16;
        Yf[(size_t)row * 512 + col] = acc[ms][ns][r] + b1[col];
    }
}

// ---------------------------------------------------------------------------
// Fused rel-pos flash attention, 512 threads (8 waves), 128 s-rows/block.
// grid (64 bh, 8 s-tiles) -> 512 blocks, 2/CU, 16 waves/CU.
// LDS-staged K / V^T / rolling 256-slot p-band, VGPR prefetch each iter.
// Fixed-max softmax (p = exp(s-40)); rel-shift via in-wave shuffles.
// Output transposed through wave-private Pscr -> dwordx4 stores.
// ---------------------------------------------------------------------------
__global__ __launch_bounds__(512) void attn_kernel(
    const ushort_t* __restrict__ qu_g, const ushort_t* __restrict__ qv_g,
    const ushort_t* __restrict__ kb, const ushort_t* __restrict__ vt_g,
    const ushort_t* __restrict__ pbf, const unsigned char* __restrict__ mask,
    ushort_t* __restrict__ xg)
{
    const int bh = blockIdx.x;            // b*8 + h
    const int s0 = blockIdx.y * 128;
    const int b = bh >> 3, h = bh & 7;
    const int tid = threadIdx.x;
    const int wave = tid >> 6, lane = tid & 63, quad = lane >> 4, l16 = lane & 15;

    __shared__ __align__(16) ushort_t Ks[64][72];
    __shared__ __align__(16) ushort_t Vts[64][72];
    __shared__ __align__(16) ushort_t Pb[256][72];
    __shared__ __align__(16) ushort_t Pscr[8][16][72];

    // Q fragments (A-operand, m = lane&15), loaded once
    const size_t qoff = ((size_t)bh * SS + s0 + wave * 16 + l16) * CC;
    short8 quA[2], qvA[2];
    quA[0] = *(const short8*)(qu_g + qoff + quad * 8);
    quA[1] = *(const short8*)(qu_g + qoff + 32 + quad * 8);
    qvA[0] = *(const short8*)(qv_g + qoff + quad * 8);
    qvA[1] = *(const short8*)(qv_g + qoff + 32 + quad * 8);

    f32x4 O[4];
    #pragma unroll
    for (int i = 0; i < 4; ++i) O[i] = (f32x4){0.f, 0.f, 0.f, 0.f};
    float lsum[4] = {0.f, 0.f, 0.f, 0.f};

    const ushort_t* kbase  = kb   + ((size_t)bh << 10) * CC;   // [t][c]
    const ushort_t* vtbase = vt_g + ((size_t)bh << 6) * SS;    // [c][s]
    const ushort_t* pbase  = pbf  + (size_t)h * PP * CC;       // [u][c]
    const unsigned char* mbase = mask + b * SS;

    const int R0base = 896 - s0;              // block band window start at t0=0
    const int uwread = 1008 - s0 - wave * 16; // +t0+us*16+l16 = global p row

    // ---- initial staging: K(t0=0), Vt(t0=0), 192-row p band ----
    {
        const int r = tid >> 3, cc = (tid & 7) * 8;
        *(uint4*)&Ks[r][cc]  = *(const uint4*)(kbase + (size_t)r * CC + cc);
        *(uint4*)&Vts[r][cc] = *(const uint4*)(vtbase + (size_t)r * SS + cc);
        #pragma unroll
        for (int i = 0; i < 3; ++i) {
            int u = tid + 512 * i; int rr = u >> 3; int c2 = (u & 7) * 8;
            int gr = R0base + rr;
            int g = gr; if (g < 0) g = 0; if (g > PP - 1) g = PP - 1;
            *(uint4*)&Pb[gr & 255][c2] = *(const uint4*)(pbase + (size_t)g * CC + c2);
        }
    }
    __syncthreads();

    for (int t0 = 0; t0 < SS; t0 += 64) {
        const bool more = (t0 + 64) < SS;
        // ---- prefetch next tile to VGPRs ----
        uint4 kp, vp, pp;
        const int r = tid >> 3, cc = (tid & 7) * 8;
        if (more) {
            kp = *(const uint4*)(kbase + (size_t)(t0 + 64 + r) * CC + cc);
            vp = *(const uint4*)(vtbase + (size_t)r * SS + t0 + 64 + cc);
            int g = R0base + t0 + 192 + r;
            if (g > PP - 1) g = PP - 1;
            pp = *(const uint4*)(pbase + (size_t)g * CC + cc);
        }

        // ---- AC = q_u . K^T ----
        f32x4 ac[4];
        #pragma unroll
        for (int ns = 0; ns < 4; ++ns) {
            ac[ns] = (f32x4){0.f, 0.f, 0.f, 0.f};
            #pragma unroll
            for (int kk = 0; kk < 2; ++kk) {
                short8 kf = *(const short8*)&Ks[ns * 16 + l16][kk * 32 + quad * 8];
                ac[ns] = MFMA(quA[kk], kf, ac[ns]);
            }
        }
        // ---- band = q_v . p_band^T (wave-local 16 x 80) ----
        f32x4 bd[5];
        #pragma unroll
        for (int us = 0; us < 5; ++us) {
            bd[us] = (f32x4){0.f, 0.f, 0.f, 0.f};
            #pragma unroll
            for (int kk = 0; kk < 2; ++kk) {
                short8 pf = *(const short8*)&Pb[(uwread + t0 + us * 16 + l16) & 255][kk * 32 + quad * 8];
                bd[us] = MFMA(qvA[kk], pf, bd[us]);
            }
        }

        // ---- shift (in-wave shuffle) + exp(s - 40) + mask; accumulate lsum ----
        bool mk[4];
        #pragma unroll
        for (int ns = 0; ns < 4; ++ns) mk[ns] = mbase[t0 + ns * 16 + l16] != 0;

        float pvv[4][4];
        #pragma unroll
        for (int rr = 0; rr < 4; ++rr) {
            const int sl = quad * 4 + rr;
            const int d = l16 + 15 - sl;
            const int srcl = quad * 16 + (d & 15);
            const bool use_hi = d >= 16;
            #pragma unroll
            for (int ns = 0; ns < 4; ++ns) {
                float lo = __shfl(bd[ns][rr], srcl, 64);
                float hi = __shfl(bd[ns + 1][rr], srcl, 64);
                float bdv = use_hi ? hi : lo;
                float p = __expf((ac[ns][rr] + bdv) * 0.125f - 40.f);
                p = mk[ns] ? 0.f : p;
                pvv[ns][rr] = p;
                lsum[rr] += p;
            }
        }

        // ---- P: C/D layout -> A layout via wave-private LDS ----
        #pragma unroll
        for (int ns = 0; ns < 4; ++ns)
            #pragma unroll
            for (int rr = 0; rr < 4; ++rr)
                Pscr[wave][quad * 4 + rr][ns * 16 + l16] = f2bf(pvv[ns][rr]);
        short8 pA0 = *(const short8*)&Pscr[wave][l16][quad * 8];
        short8 pA1 = *(const short8*)&Pscr[wave][l16][32 + quad * 8];

        // ---- O += P . V ----
        #pragma unroll
        for (int ns = 0; ns < 4; ++ns) {
            short8 v0 = *(const short8*)&Vts[ns * 16 + l16][quad * 8];
            short8 v1 = *(const short8*)&Vts[ns * 16 + l16][32 + quad * 8];
            O[ns] = MFMA(pA0, v0, O[ns]);
            O[ns] = MFMA(pA1, v1, O[ns]);
        }

        if (more) {
            __syncthreads();   // all waves done reading Ks/Vts/Pb
            *(uint4*)&Ks[r][cc]  = kp;
            *(uint4*)&Vts[r][cc] = vp;
            *(uint4*)&Pb[(R0base + t0 + 192 + r) & 255][cc] = pp;
            __syncthreads();
        }
    }

    // ---- finalize: reduce lsum over 16 lanes, O /= l, transpose via Pscr,
    //      coalesced dwordx4 stores ----
    #pragma unroll
    for (int rr = 0; rr < 4; ++rr) {
        float s = lsum[rr];
        s += __shfl_xor(s, 1, 64); s += __shfl_xor(s, 2, 64);
        s += __shfl_xor(s, 4, 64); s += __shfl_xor(s, 8, 64);
        const float inv = 1.0f / s;
        #pragma unroll
        for (int ns = 0; ns < 4; ++ns)
            Pscr[wave][quad * 4 + rr][ns * 16 + l16] = f2bf(O[ns][rr] * inv);
    }
    {
        const ushort_t* src = &Pscr[wave][lane >> 2][(lane & 3) * 16];
        uint4 u0 = *(const uint4*)src;
        uint4 u1 = *(const uint4*)(src + 8);
        const int srow = s0 + wave * 16 + (lane >> 2);
        ushort_t* dst = xg + ((size_t)b * SS + srow) * DD + h * CC + (lane & 3) * 16;
        *(uint4*)dst = u0;
        *(uint4*)(dst + 8) = u1;
    }
}

// ---------------------------------------------------------------------------
extern "C" void kernel_launch(void* const* d_in, const int* in_sizes, int n_in,
                              void* d_out, int out_size, void* d_ws, size_t ws_size,
                              hipStream_t stream)
{
    (void)in_sizes; (void)n_in; (void)out_size; (void)ws_size;

    const float* query = (const float*)d_in[0];
    const float* key_  = (const float*)d_in[1];
    const float* value = (const float*)d_in[2];
    const float* pos   = (const float*)d_in[3];
    const unsigned char* mask = (const unsigned char*)d_in[4];
    const float* Wq   = (const float*)d_in[5];
    const float* bq   = (const float*)d_in[6];
    const float* Wk   = (const float*)d_in[7];
    const float* bk   = (const float*)d_in[8];
    const float* Wv   = (const float*)d_in[9];
    const float* bv   = (const float*)d_in[10];
    const float* Wpos = (const float*)d_in[11];
    const float* Wout = (const float*)d_in[12];
    const float* bout = (const float*)d_in[13];
    const float* ub   = (const float*)d_in[14];
    const float* vb   = (const float*)d_in[15];

    const size_t NBS = (size_t)BB * SS * DD;   // 4194304
    const size_t NP  = (size_t)PP * DD;        // 1048064
    const size_t NW  = (size_t)DD * DD;        // 262144

    ushort_t* wt   = (ushort_t*)d_ws;          // 5 transposed weights
    ushort_t* qu   = wt + 5 * NW;
    ushort_t* qv   = qu + NBS;
    ushort_t* kbuf = qv + NBS;
    ushort_t* vtb  = kbuf + NBS;               // V^T [bh][c][s]
    ushort_t* pbuf = vtb + NBS;                // [h][u][c]
    ushort_t* xg   = pbuf + NP;

    ushort_t* WtO = wt + 4 * NW;

    wtrans_kernel<<<dim3(320), dim3(256), 0, stream>>>(Wq, Wk, Wv, Wpos, Wout, wt);

    qkvpos_kernel<<<dim3(832), dim3(256), 0, stream>>>(
        query, key_, value, pos, wt, bq, bk, bv, ub, vb,
        qu, qv, kbuf, vtb, pbuf);

    attn_kernel<<<dim3(64, 8), dim3(512), 0, stream>>>(qu, qv, kbuf, vtb, pbuf, mask, xg);

    outproj_kernel<<<dim3(4, 64), dim3(256), 0, stream>>>(xg, WtO, bout, (float*)d_out);
}

// Round 6
// 237.291 us; speedup vs baseline: 2.1125x; 1.0437x over previous
//
#include <hip/hip_runtime.h>
#include <math.h>

typedef unsigned short ushort_t;
typedef __attribute__((ext_vector_type(8))) short short8;
typedef __attribute__((ext_vector_type(4))) float f32x4;

#define MFMA(a,b,c) __builtin_amdgcn_mfma_f32_16x16x32_bf16((a),(b),(c),0,0,0)

// Problem constants
#define BB 8
#define SS 1024
#define DD 512
#define HH 8
#define CC 64
#define PP 2047   // 2S-1

static __device__ __forceinline__ ushort_t f2bf(float f) {
    unsigned u = __float_as_uint(f);
    u += 0x7fffu + ((u >> 16) & 1u);       // RNE
    return (ushort_t)(u >> 16);
}
static __device__ __forceinline__ unsigned pack2(float a, float b) {
    return (unsigned)f2bf(a) | ((unsigned)f2bf(b) << 16);
}

// ---------------------------------------------------------------------------
// Weight transpose+cast: W[k][n] fp32 -> Wt[n][k] bf16, 5 weights.
// ---------------------------------------------------------------------------
__global__ __launch_bounds__(256) void wtrans_kernel(
    const float* __restrict__ Wq, const float* __restrict__ Wk,
    const float* __restrict__ Wv, const float* __restrict__ Wp,
    const float* __restrict__ Wo, ushort_t* __restrict__ wt)
{
    __shared__ float T[64][65];
    const int bid = blockIdx.x, tid = threadIdx.x;
    const int wi   = bid >> 6;
    const int tile = bid & 63;
    const float* Wsrc = (wi == 0) ? Wq : (wi == 1) ? Wk : (wi == 2) ? Wv
                      : (wi == 3) ? Wp : Wo;
    ushort_t* Wdst = wt + (size_t)wi * 262144;
    const int tk0 = (tile >> 3) * 64, tn0 = (tile & 7) * 64;
    const int r = tid >> 2, c4 = (tid & 3) * 16;
    #pragma unroll
    for (int rep = 0; rep < 4; ++rep) {
        float4 f = *(const float4*)(Wsrc + (size_t)(tk0 + r) * 512 + tn0 + c4 + rep * 4);
        T[r][c4 + rep * 4 + 0] = f.x; T[r][c4 + rep * 4 + 1] = f.y;
        T[r][c4 + rep * 4 + 2] = f.z; T[r][c4 + rep * 4 + 3] = f.w;
    }
    __syncthreads();
    #pragma unroll
    for (int rep = 0; rep < 4; ++rep) {
        uint2 u;
        u.x = pack2(T[c4 + rep * 4 + 0][r], T[c4 + rep * 4 + 1][r]);
        u.y = pack2(T[c4 + rep * 4 + 2][r], T[c4 + rep * 4 + 3][r]);
        *(uint2*)(Wdst + (size_t)(tn0 + r) * 512 + tk0 + c4 + rep * 4) = u;
    }
}

// ---------------------------------------------------------------------------
// Fused Q/K/V/pos projection. 64(m)x128(n) tiles, 1664 blocks (6.5/CU).
// XCD swizzle: mt=(bid&7)+8*(bid>>5), nt=(bid>>3)&3 -> the 4 n-tiles of an
// m-tile share bid%8 (same XCD) so X is fetched once per XCD.
// 4 waves, each computes m64 x n32 (4x2 frags). BK=64, cast fused in staging.
// Vectorized epilogue: acc -> LDS (reusing staging space) -> dwordx4 stores.
// mt: [0,128) Q, [128,256) K, [256,384) V, [384,416) pos.
// ---------------------------------------------------------------------------
__global__ __launch_bounds__(256) void qkvpos_kernel(
    const float* __restrict__ Xq, const float* __restrict__ Xk,
    const float* __restrict__ Xv, const float* __restrict__ Xp,
    const ushort_t* __restrict__ wt,
    const float* __restrict__ bq, const float* __restrict__ bk,
    const float* __restrict__ bv,
    const float* __restrict__ ub, const float* __restrict__ vbias,
    ushort_t* __restrict__ qu, ushort_t* __restrict__ qvo,
    ushort_t* __restrict__ kbuf, ushort_t* __restrict__ vtb,
    ushort_t* __restrict__ pbuf)
{
    __shared__ __align__(16) ushort_t smem[64 * 72 + 128 * 72];
    ushort_t (*Xs)[72] = (ushort_t(*)[72])smem;            // [64][72]
    ushort_t (*Ws)[72] = (ushort_t(*)[72])(smem + 64 * 72);// [128][72]
    ushort_t (*Es)[136] = (ushort_t(*)[136])smem;          // epilogue [64][136]
    ushort_t (*EsT)[72] = (ushort_t(*)[72])smem;           // epilogue T [128][72]

    const int tid = threadIdx.x;
    const int wave = tid >> 6, lane = tid & 63, quad = lane >> 4, l16 = lane & 15;
    const int bid = blockIdx.x;
    const int nt = (bid >> 3) & 3;
    const int mt = (bid & 7) + 8 * (bid >> 5);
    const int n0 = nt * 128;
    int mode, mtl;
    if (mt < 128)      { mode = 0; mtl = mt; }
    else if (mt < 256) { mode = 1; mtl = mt - 128; }
    else if (mt < 384) { mode = 2; mtl = mt - 256; }
    else               { mode = 3; mtl = mt - 384; }
    const int m0 = mtl * 64;
    const float* X = (mode == 0) ? Xq : (mode == 1) ? Xk : (mode == 2) ? Xv : Xp;
    const ushort_t* W = wt + (size_t)mode * 262144;

    f32x4 acc[4][2];
    #pragma unroll
    for (int i = 0; i < 4; ++i)
        #pragma unroll
        for (int j = 0; j < 2; ++j) acc[i][j] = (f32x4){0.f, 0.f, 0.f, 0.f};

    const int xr = tid >> 2, xc = (tid & 3) * 16;   // X stage: 4 thr/row
    for (int k0 = 0; k0 < 512; k0 += 64) {
        {
            int row = m0 + xr;
            if (mode == 3 && row > PP - 1) row = PP - 1;
            const float* xp = X + (size_t)row * 512 + k0 + xc;
            float4 f0 = *(const float4*)xp;
            float4 f1 = *(const float4*)(xp + 4);
            float4 f2 = *(const float4*)(xp + 8);
            float4 f3 = *(const float4*)(xp + 12);
            uint4 a, bpk;
            a.x = pack2(f0.x, f0.y); a.y = pack2(f0.z, f0.w);
            a.z = pack2(f1.x, f1.y); a.w = pack2(f1.z, f1.w);
            bpk.x = pack2(f2.x, f2.y); bpk.y = pack2(f2.z, f2.w);
            bpk.z = pack2(f3.x, f3.y); bpk.w = pack2(f3.z, f3.w);
            *(uint4*)&Xs[xr][xc] = a;
            *(uint4*)&Xs[xr][xc + 8] = bpk;
            #pragma unroll
            for (int i = 0; i < 2; ++i) {
                int u = tid + 256 * i;
                int r = u >> 2, cc = (u & 3) * 16;
                const ushort_t* wp = W + (size_t)(n0 + r) * 512 + k0 + cc;
                *(uint4*)&Ws[r][cc]     = *(const uint4*)wp;
                *(uint4*)&Ws[r][cc + 8] = *(const uint4*)(wp + 8);
            }
        }
        __syncthreads();
        #pragma unroll
        for (int kk = 0; kk < 2; ++kk) {
            short8 av[4], bv4[2];
            #pragma unroll
            for (int ms = 0; ms < 4; ++ms)
                av[ms] = *(const short8*)&Xs[ms * 16 + l16][kk * 32 + quad * 8];
            #pragma unroll
            for (int ns = 0; ns < 2; ++ns)
                bv4[ns] = *(const short8*)&Ws[wave * 32 + ns * 16 + l16][kk * 32 + quad * 8];
            #pragma unroll
            for (int ms = 0; ms < 4; ++ms)
                #pragma unroll
                for (int ns = 0; ns < 2; ++ns)
                    acc[ms][ns] = MFMA(av[ms], bv4[ns], acc[ms][ns]);
        }
        __syncthreads();
    }

    // ---- epilogue: through LDS, vectorized global stores ----
    float b1c[2], b2c[2], b3c[2];
    #pragma unroll
    for (int ns = 0; ns < 2; ++ns) {
        const int gcol = n0 + wave * 32 + ns * 16 + l16;
        if (mode == 0) { b1c[ns] = bq[gcol]; b2c[ns] = ub[gcol]; b3c[ns] = vbias[gcol]; }
        else if (mode == 1) { b1c[ns] = bk[gcol]; }
        else if (mode == 2) { b1c[ns] = bv[gcol]; }
        else b1c[ns] = 0.f;
    }

    const int npass = (mode == 0) ? 2 : 1;
    for (int pass = 0; pass < npass; ++pass) {
        // fill
        #pragma unroll
        for (int ms = 0; ms < 4; ++ms)
        #pragma unroll
        for (int ns = 0; ns < 2; ++ns)
        #pragma unroll
        for (int r = 0; r < 4; ++r) {
            const int lrow = ms * 16 + quad * 4 + r;
            const int lcol = wave * 32 + ns * 16 + l16;
            float v = acc[ms][ns][r];
            if (mode == 0) v += b1c[ns] + (pass == 0 ? b2c[ns] : b3c[ns]);
            else if (mode != 3) v += b1c[ns];
            if (mode == 2) EsT[lcol][lrow] = f2bf(v);
            else           Es[lrow][lcol]  = f2bf(v);
        }
        __syncthreads();
        // store
        if (mode == 2) {
            const int b = m0 >> 10;
            #pragma unroll
            for (int i = 0; i < 4; ++i) {
                int u = tid + 256 * i;
                int cl = u >> 3, off8 = (u & 7) * 8;
                uint4 d = *(const uint4*)&EsT[cl][off8];
                const int gcol = n0 + cl;
                ushort_t* dst = vtb + (((size_t)(b * HH + (gcol >> 6))) * CC + (gcol & 63)) * SS
                                + (m0 & 1023) + off8;
                *(uint4*)dst = d;
            }
        } else {
            #pragma unroll
            for (int i = 0; i < 4; ++i) {
                int u = tid + 256 * i;
                int seg = u >> 3, off8 = (u & 7) * 8;
                int sl = seg >> 1, hsel = seg & 1;
                int lc = hsel * 64 + off8;
                uint4 d = *(const uint4*)&Es[sl][lc];
                const int grow = m0 + sl;
                const int gcol = n0 + lc;
                if (mode == 3) {
                    if (grow < PP) {
                        ushort_t* dst = pbuf + ((size_t)(gcol >> 6) * PP + grow) * CC + (gcol & 63);
                        *(uint4*)dst = d;
                    }
                } else {
                    size_t idx = (((size_t)(grow >> 10) * HH + (gcol >> 6)) * SS + (grow & 1023)) * CC + (gcol & 63);
                    ushort_t* dst = (mode == 1) ? (kbuf + idx)
                                  : (pass == 0 ? (qu + idx) : (qvo + idx));
                    *(uint4*)dst = d;
                }
            }
        }
        if (pass + 1 < npass) __syncthreads();
    }
}

// ---------------------------------------------------------------------------
// Out-projection: bf16 X @ WtO^T + bout -> fp32. 64x128 tiles, 512 blocks.
// Same swizzle: mt=(bid&7)+8*(bid>>5), nt=(bid>>3)&3.
// ---------------------------------------------------------------------------
__global__ __launch_bounds__(256) void outproj_kernel(
    const ushort_t* __restrict__ X, const ushort_t* __restrict__ W,
    const float* __restrict__ b1, float* __restrict__ Yf)
{
    __shared__ __align__(16) ushort_t smem[64 * 72 + 128 * 72];
    ushort_t (*Xs)[72] = (ushort_t(*)[72])smem;
    ushort_t (*Ws)[72] = (ushort_t(*)[72])(smem + 64 * 72);

    const int tid = threadIdx.x;
    const int wave = tid >> 6, lane = tid & 63, quad = lane >> 4, l16 = lane & 15;
    const int bid = blockIdx.x;
    const int nt = (bid >> 3) & 3;
    const int mtl = (bid & 7) + 8 * (bid >> 5);
    const int n0 = nt * 128, m0 = mtl * 64;

    f32x4 acc[4][2];
    #pragma unroll
    for (int i = 0; i < 4; ++i)
        #pragma unroll
        for (int j = 0; j < 2; ++j) acc[i][j] = (f32x4){0.f, 0.f, 0.f, 0.f};

    const int xr = tid >> 2, xc = (tid & 3) * 16;
    for (int k0 = 0; k0 < 512; k0 += 64) {
        {
            const ushort_t* xp = X + (size_t)(m0 + xr) * 512 + k0 + xc;
            *(uint4*)&Xs[xr][xc]     = *(const uint4*)xp;
            *(uint4*)&Xs[xr][xc + 8] = *(const uint4*)(xp + 8);
            #pragma unroll
            for (int i = 0; i < 2; ++i) {
                int u = tid + 256 * i;
                int r = u >> 2, cc = (u & 3) * 16;
                const ushort_t* wp = W + (size_t)(n0 + r) * 512 + k0 + cc;
                *(uint4*)&Ws[r][cc]     = *(const uint4*)wp;
                *(uint4*)&Ws[r][cc + 8] = *(const uint4*)(wp + 8);
            }
        }
        __syncthreads();
        #pragma unroll
        for (int kk = 0; kk < 2; ++kk) {
            short8 av[4], bv4[2];
            #pragma unroll
            for (int ms = 0; ms < 4; ++ms)
                av[ms] = *(const short8*)&Xs[ms * 16 + l16][kk * 32 + quad * 8];
            #pragma unroll
            for (int ns = 0; ns < 2; ++ns)
                bv4[ns] = *(const short8*)&Ws[wave * 32 + ns * 16 + l16][kk * 32 + quad * 8];
            #pragma unroll
            for (int ms = 0; ms < 4; ++ms)
                #pragma unroll
                for (int ns = 0; ns < 2; ++ns)
                    acc[ms][ns] = MFMA(av[ms], bv4[ns], acc[ms][ns]);
        }
        __syncthreads();
    }

    #pragma unroll
    for (int ms = 0; ms < 4; ++ms)
    #pragma unroll
    for (int ns = 0; ns < 2; ++ns)
    #pragma unroll
    for (int r = 0; r < 4; ++r) {
        const int row = m0 + ms * 16 + quad * 4 + r;
        const int col = n0 + wave * 32 + ns * 16 + l16;
        Yf[(size_t)row * 512 + col] = acc[ms][ns][r] + b1[col];
    }
}

// ---------------------------------------------------------------------------
// Fused rel-pos flash attention, 512 threads (8 waves), 128 s-rows/block.
// grid (64 bh, 8 s-tiles) -> 512 blocks, 2/CU, 16 waves/CU.
// LDS-staged K / V^T / rolling 256-slot p-band, VGPR prefetch each iter.
// Fixed-max softmax (p = exp(s-40)); rel-shift via in-wave shuffles.
// Output transposed through wave-private Pscr -> dwordx4 stores.
// ---------------------------------------------------------------------------
__global__ __launch_bounds__(512) void attn_kernel(
    const ushort_t* __restrict__ qu_g, const ushort_t* __restrict__ qv_g,
    const ushort_t* __restrict__ kb, const ushort_t* __restrict__ vt_g,
    const ushort_t* __restrict__ pbf, const unsigned char* __restrict__ mask,
    ushort_t* __restrict__ xg)
{
    const int bh = blockIdx.x;            // b*8 + h
    const int s0 = blockIdx.y * 128;
    const int b = bh >> 3, h = bh & 7;
    const int tid = threadIdx.x;
    const int wave = tid >> 6, lane = tid & 63, quad = lane >> 4, l16 = lane & 15;

    __shared__ __align__(16) ushort_t Ks[64][72];
    __shared__ __align__(16) ushort_t Vts[64][72];
    __shared__ __align__(16) ushort_t Pb[256][72];
    __shared__ __align__(16) ushort_t Pscr[8][16][72];

    // Q fragments (A-operand, m = lane&15), loaded once
    const size_t qoff = ((size_t)bh * SS + s0 + wave * 16 + l16) * CC;
    short8 quA[2], qvA[2];
    quA[0] = *(const short8*)(qu_g + qoff + quad * 8);
    quA[1] = *(const short8*)(qu_g + qoff + 32 + quad * 8);
    qvA[0] = *(const short8*)(qv_g + qoff + quad * 8);
    qvA[1] = *(const short8*)(qv_g + qoff + 32 + quad * 8);

    f32x4 O[4];
    #pragma unroll
    for (int i = 0; i < 4; ++i) O[i] = (f32x4){0.f, 0.f, 0.f, 0.f};
    float lsum[4] = {0.f, 0.f, 0.f, 0.f};

    const ushort_t* kbase  = kb   + ((size_t)bh << 10) * CC;   // [t][c]
    const ushort_t* vtbase = vt_g + ((size_t)bh << 6) * SS;    // [c][s]
    const ushort_t* pbase  = pbf  + (size_t)h * PP * CC;       // [u][c]
    const unsigned char* mbase = mask + b * SS;

    const int R0base = 896 - s0;              // block band window start at t0=0
    const int uwread = 1008 - s0 - wave * 16; // +t0+us*16+l16 = global p row

    // ---- initial staging: K(t0=0), Vt(t0=0), 192-row p band ----
    {
        const int r = tid >> 3, cc = (tid & 7) * 8;
        *(uint4*)&Ks[r][cc]  = *(const uint4*)(kbase + (size_t)r * CC + cc);
        *(uint4*)&Vts[r][cc] = *(const uint4*)(vtbase + (size_t)r * SS + cc);
        #pragma unroll
        for (int i = 0; i < 3; ++i) {
            int u = tid + 512 * i; int rr = u >> 3; int c2 = (u & 7) * 8;
            int gr = R0base + rr;
            int g = gr; if (g < 0) g = 0; if (g > PP - 1) g = PP - 1;
            *(uint4*)&Pb[gr & 255][c2] = *(const uint4*)(pbase + (size_t)g * CC + c2);
        }
    }
    __syncthreads();

    for (int t0 = 0; t0 < SS; t0 += 64) {
        const bool more = (t0 + 64) < SS;
        // ---- prefetch next tile to VGPRs ----
        uint4 kp, vp, pp;
        const int r = tid >> 3, cc = (tid & 7) * 8;
        if (more) {
            kp = *(const uint4*)(kbase + (size_t)(t0 + 64 + r) * CC + cc);
            vp = *(const uint4*)(vtbase + (size_t)r * SS + t0 + 64 + cc);
            int g = R0base + t0 + 192 + r;
            if (g > PP - 1) g = PP - 1;
            pp = *(const uint4*)(pbase + (size_t)g * CC + cc);
        }

        // ---- AC = q_u . K^T ----
        f32x4 ac[4];
        #pragma unroll
        for (int ns = 0; ns < 4; ++ns) {
            ac[ns] = (f32x4){0.f, 0.f, 0.f, 0.f};
            #pragma unroll
            for (int kk = 0; kk < 2; ++kk) {
                short8 kf = *(const short8*)&Ks[ns * 16 + l16][kk * 32 + quad * 8];
                ac[ns] = MFMA(quA[kk], kf, ac[ns]);
            }
        }
        // ---- band = q_v . p_band^T (wave-local 16 x 80) ----
        f32x4 bd[5];
        #pragma unroll
        for (int us = 0; us < 5; ++us) {
            bd[us] = (f32x4){0.f, 0.f, 0.f, 0.f};
            #pragma unroll
            for (int kk = 0; kk < 2; ++kk) {
                short8 pf = *(const short8*)&Pb[(uwread + t0 + us * 16 + l16) & 255][kk * 32 + quad * 8];
                bd[us] = MFMA(qvA[kk], pf, bd[us]);
            }
        }

        // ---- shift (in-wave shuffle) + exp(s - 40) + mask; accumulate lsum ----
        bool mk[4];
        #pragma unroll
        for (int ns = 0; ns < 4; ++ns) mk[ns] = mbase[t0 + ns * 16 + l16] != 0;

        float pvv[4][4];
        #pragma unroll
        for (int rr = 0; rr < 4; ++rr) {
            const int sl = quad * 4 + rr;
            const int d = l16 + 15 - sl;
            const int srcl = quad * 16 + (d & 15);
            const bool use_hi = d >= 16;
            #pragma unroll
            for (int ns = 0; ns < 4; ++ns) {
                float lo = __shfl(bd[ns][rr], srcl, 64);
                float hi = __shfl(bd[ns + 1][rr], srcl, 64);
                float bdv = use_hi ? hi : lo;
                float p = __expf((ac[ns][rr] + bdv) * 0.125f - 40.f);
                p = mk[ns] ? 0.f : p;
                pvv[ns][rr] = p;
                lsum[rr] += p;
            }
        }

        // ---- P: C/D layout -> A layout via wave-private LDS ----
        #pragma unroll
        for (int ns = 0; ns < 4; ++ns)
            #pragma unroll
            for (int rr = 0; rr < 4; ++rr)
                Pscr[wave][quad * 4 + rr][ns * 16 + l16] = f2bf(pvv[ns][rr]);
        short8 pA0 = *(const short8*)&Pscr[wave][l16][quad * 8];
        short8 pA1 = *(const short8*)&Pscr[wave][l16][32 + quad * 8];

        // ---- O += P . V ----
        #pragma unroll
        for (int ns = 0; ns < 4; ++ns) {
            short8 v0 = *(const short8*)&Vts[ns * 16 + l16][quad * 8];
            short8 v1 = *(const short8*)&Vts[ns * 16 + l16][32 + quad * 8];
            O[ns] = MFMA(pA0, v0, O[ns]);
            O[ns] = MFMA(pA1, v1, O[ns]);
        }

        if (more) {
            __syncthreads();   // all waves done reading Ks/Vts/Pb
            *(uint4*)&Ks[r][cc]  = kp;
            *(uint4*)&Vts[r][cc] = vp;
            *(uint4*)&Pb[(R0base + t0 + 192 + r) & 255][cc] = pp;
            __syncthreads();
        }
    }

    // ---- finalize: reduce lsum over 16 lanes, O /= l, transpose via Pscr,
    //      coalesced dwordx4 stores ----
    #pragma unroll
    for (int rr = 0; rr < 4; ++rr) {
        float s = lsum[rr];
        s += __shfl_xor(s, 1, 64); s += __shfl_xor(s, 2, 64);
        s += __shfl_xor(s, 4, 64); s += __shfl_xor(s, 8, 64);
        const float inv = 1.0f / s;
        #pragma unroll
        for (int ns = 0; ns < 4; ++ns)
            Pscr[wave][quad * 4 + rr][ns * 16 + l16] = f2bf(O[ns][rr] * inv);
    }
    {
        const ushort_t* src = &Pscr[wave][lane >> 2][(lane & 3) * 16];
        uint4 u0 = *(const uint4*)src;
        uint4 u1 = *(const uint4*)(src + 8);
        const int srow = s0 + wave * 16 + (lane >> 2);
        ushort_t* dst = xg + ((size_t)b * SS + srow) * DD + h * CC + (lane & 3) * 16;
        *(uint4*)dst = u0;
        *(uint4*)(dst + 8) = u1;
    }
}

// ---------------------------------------------------------------------------
extern "C" void kernel_launch(void* const* d_in, const int* in_sizes, int n_in,
                              void* d_out, int out_size, void* d_ws, size_t ws_size,
                              hipStream_t stream)
{
    (void)in_sizes; (void)n_in; (void)out_size; (void)ws_size;

    const float* query = (const float*)d_in[0];
    const float* key_  = (const float*)d_in[1];
    const float* value = (const float*)d_in[2];
    const float* pos   = (const float*)d_in[3];
    const unsigned char* mask = (const unsigned char*)d_in[4];
    const float* Wq   = (const float*)d_in[5];
    const float* bq   = (const float*)d_in[6];
    const float* Wk   = (const float*)d_in[7];
    const float* bk   = (const float*)d_in[8];
    const float* Wv   = (const float*)d_in[9];
    const float* bv   = (const float*)d_in[10];
    const float* Wpos = (const float*)d_in[11];
    const float* Wout = (const float*)d_in[12];
    const float* bout = (const float*)d_in[13];
    const float* ub   = (const float*)d_in[14];
    const float* vb   = (const float*)d_in[15];

    const size_t NBS = (size_t)BB * SS * DD;   // 4194304
    const size_t NP  = (size_t)PP * DD;        // 1048064
    const size_t NW  = (size_t)DD * DD;        // 262144

    ushort_t* wt   = (ushort_t*)d_ws;          // 5 transposed weights
    ushort_t* qu   = wt + 5 * NW;
    ushort_t* qv   = qu + NBS;
    ushort_t* kbuf = qv + NBS;
    ushort_t* vtb  = kbuf + NBS;               // V^T [bh][c][s]
    ushort_t* pbuf = vtb + NBS;                // [h][u][c]
    ushort_t* xg   = pbuf + NP;

    ushort_t* WtO = wt + 4 * NW;

    wtrans_kernel<<<dim3(320), dim3(256), 0, stream>>>(Wq, Wk, Wv, Wpos, Wout, wt);

    qkvpos_kernel<<<dim3(1664), dim3(256), 0, stream>>>(
        query, key_, value, pos, wt, bq, bk, bv, ub, vb,
        qu, qv, kbuf, vtb, pbuf);

    attn_kernel<<<dim3(64, 8), dim3(512), 0, stream>>>(qu, qv, kbuf, vtb, pbuf, mask, xg);

    outproj_kernel<<<dim3(512), dim3(256), 0, stream>>>(xg, WtO, bout, (float*)d_out);
}

// Round 7
// 225.391 us; speedup vs baseline: 2.2241x; 1.0528x over previous
//
#include <hip/hip_runtime.h>
#include <math.h>

typedef unsigned short ushort_t;
typedef __attribute__((ext_vector_type(8))) short short8;
typedef __attribute__((ext_vector_type(4))) float f32x4;

#define MFMA(a,b,c) __builtin_amdgcn_mfma_f32_16x16x32_bf16((a),(b),(c),0,0,0)

// Problem constants
#define BB 8
#define SS 1024
#define DD 512
#define HH 8
#define CC 64
#define PP 2047   // 2S-1

static __device__ __forceinline__ ushort_t f2bf(float f) {
    unsigned u = __float_as_uint(f);
    u += 0x7fffu + ((u >> 16) & 1u);       // RNE
    return (ushort_t)(u >> 16);
}
static __device__ __forceinline__ unsigned pack2(float a, float b) {
    return (unsigned)f2bf(a) | ((unsigned)f2bf(b) << 16);
}

// ---------------------------------------------------------------------------
// Weight transpose+cast: W[k][n] fp32 -> Wt[n][k] bf16, 5 weights.
// ---------------------------------------------------------------------------
__global__ __launch_bounds__(256) void wtrans_kernel(
    const float* __restrict__ Wq, const float* __restrict__ Wk,
    const float* __restrict__ Wv, const float* __restrict__ Wp,
    const float* __restrict__ Wo, ushort_t* __restrict__ wt)
{
    __shared__ float T[64][65];
    const int bid = blockIdx.x, tid = threadIdx.x;
    const int wi   = bid >> 6;
    const int tile = bid & 63;
    const float* Wsrc = (wi == 0) ? Wq : (wi == 1) ? Wk : (wi == 2) ? Wv
                      : (wi == 3) ? Wp : Wo;
    ushort_t* Wdst = wt + (size_t)wi * 262144;
    const int tk0 = (tile >> 3) * 64, tn0 = (tile & 7) * 64;
    const int r = tid >> 2, c4 = (tid & 3) * 16;
    #pragma unroll
    for (int rep = 0; rep < 4; ++rep) {
        float4 f = *(const float4*)(Wsrc + (size_t)(tk0 + r) * 512 + tn0 + c4 + rep * 4);
        T[r][c4 + rep * 4 + 0] = f.x; T[r][c4 + rep * 4 + 1] = f.y;
        T[r][c4 + rep * 4 + 2] = f.z; T[r][c4 + rep * 4 + 3] = f.w;
    }
    __syncthreads();
    #pragma unroll
    for (int rep = 0; rep < 4; ++rep) {
        uint2 u;
        u.x = pack2(T[c4 + rep * 4 + 0][r], T[c4 + rep * 4 + 1][r]);
        u.y = pack2(T[c4 + rep * 4 + 2][r], T[c4 + rep * 4 + 3][r]);
        *(uint2*)(Wdst + (size_t)(tn0 + r) * 512 + tk0 + c4 + rep * 4) = u;
    }
}

// ---------------------------------------------------------------------------
// Fused Q/K/V/pos projection. 64(m)x128(n) tiles, 1664 blocks, XCD swizzle.
// VGPR-prefetch double-buffering: next k-tile's global loads issue BEFORE the
// current tile's MFMA, so barriers only drain LDS writes (attn-style).
// 4 waves, each m64 x n32 (4x2 frags). BK=64, fp32->bf16 cast in staging.
// Vectorized epilogue through LDS. mt: [0,128) Q, [128,256) K, [256,384) V,
// [384,416) pos.
// ---------------------------------------------------------------------------
__global__ __launch_bounds__(256) void qkvpos_kernel(
    const float* __restrict__ Xq, const float* __restrict__ Xk,
    const float* __restrict__ Xv, const float* __restrict__ Xp,
    const ushort_t* __restrict__ wt,
    const float* __restrict__ bq, const float* __restrict__ bk,
    const float* __restrict__ bv,
    const float* __restrict__ ub, const float* __restrict__ vbias,
    ushort_t* __restrict__ qu, ushort_t* __restrict__ qvo,
    ushort_t* __restrict__ kbuf, ushort_t* __restrict__ vtb,
    ushort_t* __restrict__ pbuf)
{
    __shared__ __align__(16) ushort_t smem[64 * 72 + 128 * 72];
    ushort_t (*Xs)[72] = (ushort_t(*)[72])smem;            // [64][72]
    ushort_t (*Ws)[72] = (ushort_t(*)[72])(smem + 64 * 72);// [128][72]
    ushort_t (*Es)[136] = (ushort_t(*)[136])smem;          // epilogue [64][136]
    ushort_t (*EsT)[72] = (ushort_t(*)[72])smem;           // epilogue T [128][72]

    const int tid = threadIdx.x;
    const int wave = tid >> 6, lane = tid & 63, quad = lane >> 4, l16 = lane & 15;
    const int bid = blockIdx.x;
    const int nt = (bid >> 3) & 3;
    const int mt = (bid & 7) + 8 * (bid >> 5);
    const int n0 = nt * 128;
    int mode, mtl;
    if (mt < 128)      { mode = 0; mtl = mt; }
    else if (mt < 256) { mode = 1; mtl = mt - 128; }
    else if (mt < 384) { mode = 2; mtl = mt - 256; }
    else               { mode = 3; mtl = mt - 384; }
    const int m0 = mtl * 64;
    const float* X = (mode == 0) ? Xq : (mode == 1) ? Xk : (mode == 2) ? Xv : Xp;
    const ushort_t* W = wt + (size_t)mode * 262144;

    f32x4 acc[4][2];
    #pragma unroll
    for (int i = 0; i < 4; ++i)
        #pragma unroll
        for (int j = 0; j < 2; ++j) acc[i][j] = (f32x4){0.f, 0.f, 0.f, 0.f};

    const int xr = tid >> 2, xc = (tid & 3) * 16;   // X stage: 4 thr/row
    int xrow = m0 + xr;
    if (mode == 3 && xrow > PP - 1) xrow = PP - 1;
    const int wr0 = tid >> 2, wc0 = (tid & 3) * 16;          // W i=0
    const int wr1 = (tid + 256) >> 2, wc1 = wc0;             // W i=1

    // ---- initial stage k0=0 ----
    {
        const float* xp = X + (size_t)xrow * 512 + xc;
        float4 f0 = *(const float4*)xp;
        float4 f1 = *(const float4*)(xp + 4);
        float4 f2 = *(const float4*)(xp + 8);
        float4 f3 = *(const float4*)(xp + 12);
        uint4 a, bpk;
        a.x = pack2(f0.x, f0.y); a.y = pack2(f0.z, f0.w);
        a.z = pack2(f1.x, f1.y); a.w = pack2(f1.z, f1.w);
        bpk.x = pack2(f2.x, f2.y); bpk.y = pack2(f2.z, f2.w);
        bpk.z = pack2(f3.x, f3.y); bpk.w = pack2(f3.z, f3.w);
        *(uint4*)&Xs[xr][xc] = a;
        *(uint4*)&Xs[xr][xc + 8] = bpk;
        const ushort_t* wp0 = W + (size_t)(n0 + wr0) * 512 + wc0;
        const ushort_t* wp1 = W + (size_t)(n0 + wr1) * 512 + wc1;
        *(uint4*)&Ws[wr0][wc0]     = *(const uint4*)wp0;
        *(uint4*)&Ws[wr0][wc0 + 8] = *(const uint4*)(wp0 + 8);
        *(uint4*)&Ws[wr1][wc1]     = *(const uint4*)wp1;
        *(uint4*)&Ws[wr1][wc1 + 8] = *(const uint4*)(wp1 + 8);
    }
    __syncthreads();

    for (int k0 = 0; k0 < 512; k0 += 64) {
        const bool more = (k0 + 64) < 512;
        // ---- prefetch next k-tile into VGPRs (overlaps compute below) ----
        uint4 xa, xb, wv0a, wv0b, wv1a, wv1b;
        if (more) {
            const float* xp = X + (size_t)xrow * 512 + k0 + 64 + xc;
            float4 f0 = *(const float4*)xp;
            float4 f1 = *(const float4*)(xp + 4);
            float4 f2 = *(const float4*)(xp + 8);
            float4 f3 = *(const float4*)(xp + 12);
            xa.x = pack2(f0.x, f0.y); xa.y = pack2(f0.z, f0.w);
            xa.z = pack2(f1.x, f1.y); xa.w = pack2(f1.z, f1.w);
            xb.x = pack2(f2.x, f2.y); xb.y = pack2(f2.z, f2.w);
            xb.z = pack2(f3.x, f3.y); xb.w = pack2(f3.z, f3.w);
            const ushort_t* wp0 = W + (size_t)(n0 + wr0) * 512 + k0 + 64 + wc0;
            const ushort_t* wp1 = W + (size_t)(n0 + wr1) * 512 + k0 + 64 + wc1;
            wv0a = *(const uint4*)wp0; wv0b = *(const uint4*)(wp0 + 8);
            wv1a = *(const uint4*)wp1; wv1b = *(const uint4*)(wp1 + 8);
        }
        // ---- compute on current LDS tile ----
        #pragma unroll
        for (int kk = 0; kk < 2; ++kk) {
            short8 av[4], bv4[2];
            #pragma unroll
            for (int ms = 0; ms < 4; ++ms)
                av[ms] = *(const short8*)&Xs[ms * 16 + l16][kk * 32 + quad * 8];
            #pragma unroll
            for (int ns = 0; ns < 2; ++ns)
                bv4[ns] = *(const short8*)&Ws[wave * 32 + ns * 16 + l16][kk * 32 + quad * 8];
            #pragma unroll
            for (int ms = 0; ms < 4; ++ms)
                #pragma unroll
                for (int ns = 0; ns < 2; ++ns)
                    acc[ms][ns] = MFMA(av[ms], bv4[ns], acc[ms][ns]);
        }
        if (more) {
            __syncthreads();
            *(uint4*)&Xs[xr][xc]       = xa;
            *(uint4*)&Xs[xr][xc + 8]   = xb;
            *(uint4*)&Ws[wr0][wc0]     = wv0a;
            *(uint4*)&Ws[wr0][wc0 + 8] = wv0b;
            *(uint4*)&Ws[wr1][wc1]     = wv1a;
            *(uint4*)&Ws[wr1][wc1 + 8] = wv1b;
            __syncthreads();
        }
    }
    __syncthreads();   // all compute reads done before smem reuse

    // ---- epilogue: through LDS, vectorized global stores ----
    float b1c[2], b2c[2], b3c[2];
    #pragma unroll
    for (int ns = 0; ns < 2; ++ns) {
        const int gcol = n0 + wave * 32 + ns * 16 + l16;
        if (mode == 0) { b1c[ns] = bq[gcol]; b2c[ns] = ub[gcol]; b3c[ns] = vbias[gcol]; }
        else if (mode == 1) { b1c[ns] = bk[gcol]; }
        else if (mode == 2) { b1c[ns] = bv[gcol]; }
        else b1c[ns] = 0.f;
    }

    const int npass = (mode == 0) ? 2 : 1;
    for (int pass = 0; pass < npass; ++pass) {
        // fill
        #pragma unroll
        for (int ms = 0; ms < 4; ++ms)
        #pragma unroll
        for (int ns = 0; ns < 2; ++ns)
        #pragma unroll
        for (int r = 0; r < 4; ++r) {
            const int lrow = ms * 16 + quad * 4 + r;
            const int lcol = wave * 32 + ns * 16 + l16;
            float v = acc[ms][ns][r];
            if (mode == 0) v += b1c[ns] + (pass == 0 ? b2c[ns] : b3c[ns]);
            else if (mode != 3) v += b1c[ns];
            if (mode == 2) EsT[lcol][lrow] = f2bf(v);
            else           Es[lrow][lcol]  = f2bf(v);
        }
        __syncthreads();
        // store
        if (mode == 2) {
            const int b = m0 >> 10;
            #pragma unroll
            for (int i = 0; i < 4; ++i) {
                int u = tid + 256 * i;
                int cl = u >> 3, off8 = (u & 7) * 8;
                uint4 d = *(const uint4*)&EsT[cl][off8];
                const int gcol = n0 + cl;
                ushort_t* dst = vtb + (((size_t)(b * HH + (gcol >> 6))) * CC + (gcol & 63)) * SS
                                + (m0 & 1023) + off8;
                *(uint4*)dst = d;
            }
        } else {
            #pragma unroll
            for (int i = 0; i < 4; ++i) {
                int u = tid + 256 * i;
                int seg = u >> 3, off8 = (u & 7) * 8;
                int sl = seg >> 1, hsel = seg & 1;
                int lc = hsel * 64 + off8;
                uint4 d = *(const uint4*)&Es[sl][lc];
                const int grow = m0 + sl;
                const int gcol = n0 + lc;
                if (mode == 3) {
                    if (grow < PP) {
                        ushort_t* dst = pbuf + ((size_t)(gcol >> 6) * PP + grow) * CC + (gcol & 63);
                        *(uint4*)dst = d;
                    }
                } else {
                    size_t idx = (((size_t)(grow >> 10) * HH + (gcol >> 6)) * SS + (grow & 1023)) * CC + (gcol & 63);
                    ushort_t* dst = (mode == 1) ? (kbuf + idx)
                                  : (pass == 0 ? (qu + idx) : (qvo + idx));
                    *(uint4*)dst = d;
                }
            }
        }
        if (pass + 1 < npass) __syncthreads();
    }
}

// ---------------------------------------------------------------------------
// Out-projection: bf16 X @ WtO^T + bout -> fp32. 64x128 tiles, 512 blocks,
// XCD swizzle, VGPR-prefetch double-buffering.
// ---------------------------------------------------------------------------
__global__ __launch_bounds__(256) void outproj_kernel(
    const ushort_t* __restrict__ X, const ushort_t* __restrict__ W,
    const float* __restrict__ b1, float* __restrict__ Yf)
{
    __shared__ __align__(16) ushort_t smem[64 * 72 + 128 * 72];
    ushort_t (*Xs)[72] = (ushort_t(*)[72])smem;
    ushort_t (*Ws)[72] = (ushort_t(*)[72])(smem + 64 * 72);

    const int tid = threadIdx.x;
    const int wave = tid >> 6, lane = tid & 63, quad = lane >> 4, l16 = lane & 15;
    const int bid = blockIdx.x;
    const int nt = (bid >> 3) & 3;
    const int mtl = (bid & 7) + 8 * (bid >> 5);
    const int n0 = nt * 128, m0 = mtl * 64;

    f32x4 acc[4][2];
    #pragma unroll
    for (int i = 0; i < 4; ++i)
        #pragma unroll
        for (int j = 0; j < 2; ++j) acc[i][j] = (f32x4){0.f, 0.f, 0.f, 0.f};

    const int xr = tid >> 2, xc = (tid & 3) * 16;
    const int wr0 = tid >> 2, wc0 = (tid & 3) * 16;
    const int wr1 = (tid + 256) >> 2, wc1 = wc0;

    {
        const ushort_t* xp = X + (size_t)(m0 + xr) * 512 + xc;
        *(uint4*)&Xs[xr][xc]     = *(const uint4*)xp;
        *(uint4*)&Xs[xr][xc + 8] = *(const uint4*)(xp + 8);
        const ushort_t* wp0 = W + (size_t)(n0 + wr0) * 512 + wc0;
        const ushort_t* wp1 = W + (size_t)(n0 + wr1) * 512 + wc1;
        *(uint4*)&Ws[wr0][wc0]     = *(const uint4*)wp0;
        *(uint4*)&Ws[wr0][wc0 + 8] = *(const uint4*)(wp0 + 8);
        *(uint4*)&Ws[wr1][wc1]     = *(const uint4*)wp1;
        *(uint4*)&Ws[wr1][wc1 + 8] = *(const uint4*)(wp1 + 8);
    }
    __syncthreads();

    for (int k0 = 0; k0 < 512; k0 += 64) {
        const bool more = (k0 + 64) < 512;
        uint4 xa, xb, wv0a, wv0b, wv1a, wv1b;
        if (more) {
            const ushort_t* xp = X + (size_t)(m0 + xr) * 512 + k0 + 64 + xc;
            xa = *(const uint4*)xp;
            xb = *(const uint4*)(xp + 8);
            const ushort_t* wp0 = W + (size_t)(n0 + wr0) * 512 + k0 + 64 + wc0;
            const ushort_t* wp1 = W + (size_t)(n0 + wr1) * 512 + k0 + 64 + wc1;
            wv0a = *(const uint4*)wp0; wv0b = *(const uint4*)(wp0 + 8);
            wv1a = *(const uint4*)wp1; wv1b = *(const uint4*)(wp1 + 8);
        }
        #pragma unroll
        for (int kk = 0; kk < 2; ++kk) {
            short8 av[4], bv4[2];
            #pragma unroll
            for (int ms = 0; ms < 4; ++ms)
                av[ms] = *(const short8*)&Xs[ms * 16 + l16][kk * 32 + quad * 8];
            #pragma unroll
            for (int ns = 0; ns < 2; ++ns)
                bv4[ns] = *(const short8*)&Ws[wave * 32 + ns * 16 + l16][kk * 32 + quad * 8];
            #pragma unroll
            for (int ms = 0; ms < 4; ++ms)
                #pragma unroll
                for (int ns = 0; ns < 2; ++ns)
                    acc[ms][ns] = MFMA(av[ms], bv4[ns], acc[ms][ns]);
        }
        if (more) {
            __syncthreads();
            *(uint4*)&Xs[xr][xc]       = xa;
            *(uint4*)&Xs[xr][xc + 8]   = xb;
            *(uint4*)&Ws[wr0][wc0]     = wv0a;
            *(uint4*)&Ws[wr0][wc0 + 8] = wv0b;
            *(uint4*)&Ws[wr1][wc1]     = wv1a;
            *(uint4*)&Ws[wr1][wc1 + 8] = wv1b;
            __syncthreads();
        }
    }

    #pragma unroll
    for (int ms = 0; ms < 4; ++ms)
    #pragma unroll
    for (int ns = 0; ns < 2; ++ns)
    #pragma unroll
    for (int r = 0; r < 4; ++r) {
        const int row = m0 + ms * 16 + quad * 4 + r;
        const int col = n0 + wave * 32 + ns * 16 + l16;
        Yf[(size_t)row * 512 + col] = acc[ms][ns][r] + b1[col];
    }
}

// ---------------------------------------------------------------------------
// Fused rel-pos flash attention, 512 threads (8 waves), 128 s-rows/block.
// grid (64 bh, 8 s-tiles) -> 512 blocks, 2/CU, 16 waves/CU.
// LDS-staged K / V^T / rolling 256-slot p-band, VGPR prefetch each iter.
// Fixed-max softmax (p = exp(s-40)); rel-shift via in-wave shuffles.
// Output transposed through wave-private Pscr -> dwordx4 stores.
// ---------------------------------------------------------------------------
__global__ __launch_bounds__(512) void attn_kernel(
    const ushort_t* __restrict__ qu_g, const ushort_t* __restrict__ qv_g,
    const ushort_t* __restrict__ kb, const ushort_t* __restrict__ vt_g,
    const ushort_t* __restrict__ pbf, const unsigned char* __restrict__ mask,
    ushort_t* __restrict__ xg)
{
    const int bh = blockIdx.x;            // b*8 + h
    const int s0 = blockIdx.y * 128;
    const int b = bh >> 3, h = bh & 7;
    const int tid = threadIdx.x;
    const int wave = tid >> 6, lane = tid & 63, quad = lane >> 4, l16 = lane & 15;

    __shared__ __align__(16) ushort_t Ks[64][72];
    __shared__ __align__(16) ushort_t Vts[64][72];
    __shared__ __align__(16) ushort_t Pb[256][72];
    __shared__ __align__(16) ushort_t Pscr[8][16][72];

    // Q fragments (A-operand, m = lane&15), loaded once
    const size_t qoff = ((size_t)bh * SS + s0 + wave * 16 + l16) * CC;
    short8 quA[2], qvA[2];
    quA[0] = *(const short8*)(qu_g + qoff + quad * 8);
    quA[1] = *(const short8*)(qu_g + qoff + 32 + quad * 8);
    qvA[0] = *(const short8*)(qv_g + qoff + quad * 8);
    qvA[1] = *(const short8*)(qv_g + qoff + 32 + quad * 8);

    f32x4 O[4];
    #pragma unroll
    for (int i = 0; i < 4; ++i) O[i] = (f32x4){0.f, 0.f, 0.f, 0.f};
    float lsum[4] = {0.f, 0.f, 0.f, 0.f};

    const ushort_t* kbase  = kb   + ((size_t)bh << 10) * CC;   // [t][c]
    const ushort_t* vtbase = vt_g + ((size_t)bh << 6) * SS;    // [c][s]
    const ushort_t* pbase  = pbf  + (size_t)h * PP * CC;       // [u][c]
    const unsigned char* mbase = mask + b * SS;

    const int R0base = 896 - s0;              // block band window start at t0=0
    const int uwread = 1008 - s0 - wave * 16; // +t0+us*16+l16 = global p row

    // ---- initial staging: K(t0=0), Vt(t0=0), 192-row p band ----
    {
        const int r = tid >> 3, cc = (tid & 7) * 8;
        *(uint4*)&Ks[r][cc]  = *(const uint4*)(kbase + (size_t)r * CC + cc);
        *(uint4*)&Vts[r][cc] = *(const uint4*)(vtbase + (size_t)r * SS + cc);
        #pragma unroll
        for (int i = 0; i < 3; ++i) {
            int u = tid + 512 * i; int rr = u >> 3; int c2 = (u & 7) * 8;
            int gr = R0base + rr;
            int g = gr; if (g < 0) g = 0; if (g > PP - 1) g = PP - 1;
            *(uint4*)&Pb[gr & 255][c2] = *(const uint4*)(pbase + (size_t)g * CC + c2);
        }
    }
    __syncthreads();

    for (int t0 = 0; t0 < SS; t0 += 64) {
        const bool more = (t0 + 64) < SS;
        // ---- prefetch next tile to VGPRs ----
        uint4 kp, vp, pp;
        const int r = tid >> 3, cc = (tid & 7) * 8;
        if (more) {
            kp = *(const uint4*)(kbase + (size_t)(t0 + 64 + r) * CC + cc);
            vp = *(const uint4*)(vtbase + (size_t)r * SS + t0 + 64 + cc);
            int g = R0base + t0 + 192 + r;
            if (g > PP - 1) g = PP - 1;
            pp = *(const uint4*)(pbase + (size_t)g * CC + cc);
        }

        // ---- AC = q_u . K^T ----
        f32x4 ac[4];
        #pragma unroll
        for (int ns = 0; ns < 4; ++ns) {
            ac[ns] = (f32x4){0.f, 0.f, 0.f, 0.f};
            #pragma unroll
            for (int kk = 0; kk < 2; ++kk) {
                short8 kf = *(const short8*)&Ks[ns * 16 + l16][kk * 32 + quad * 8];
                ac[ns] = MFMA(quA[kk], kf, ac[ns]);
            }
        }
        // ---- band = q_v . p_band^T (wave-local 16 x 80) ----
        f32x4 bd[5];
        #pragma unroll
        for (int us = 0; us < 5; ++us) {
            bd[us] = (f32x4){0.f, 0.f, 0.f, 0.f};
            #pragma unroll
            for (int kk = 0; kk < 2; ++kk) {
                short8 pf = *(const short8*)&Pb[(uwread + t0 + us * 16 + l16) & 255][kk * 32 + quad * 8];
                bd[us] = MFMA(qvA[kk], pf, bd[us]);
            }
        }

        // ---- shift (in-wave shuffle) + exp(s - 40) + mask; accumulate lsum ----
        bool mk[4];
        #pragma unroll
        for (int ns = 0; ns < 4; ++ns) mk[ns] = mbase[t0 + ns * 16 + l16] != 0;

        float pvv[4][4];
        #pragma unroll
        for (int rr = 0; rr < 4; ++rr) {
            const int sl = quad * 4 + rr;
            const int d = l16 + 15 - sl;
            const int srcl = quad * 16 + (d & 15);
            const bool use_hi = d >= 16;
            #pragma unroll
            for (int ns = 0; ns < 4; ++ns) {
                float lo = __shfl(bd[ns][rr], srcl, 64);
                float hi = __shfl(bd[ns + 1][rr], srcl, 64);
                float bdv = use_hi ? hi : lo;
                float p = __expf((ac[ns][rr] + bdv) * 0.125f - 40.f);
                p = mk[ns] ? 0.f : p;
                pvv[ns][rr] = p;
                lsum[rr] += p;
            }
        }

        // ---- P: C/D layout -> A layout via wave-private LDS ----
        #pragma unroll
        for (int ns = 0; ns < 4; ++ns)
            #pragma unroll
            for (int rr = 0; rr < 4; ++rr)
                Pscr[wave][quad * 4 + rr][ns * 16 + l16] = f2bf(pvv[ns][rr]);
        short8 pA0 = *(const short8*)&Pscr[wave][l16][quad * 8];
        short8 pA1 = *(const short8*)&Pscr[wave][l16][32 + quad * 8];

        // ---- O += P . V ----
        #pragma unroll
        for (int ns = 0; ns < 4; ++ns) {
            short8 v0 = *(const short8*)&Vts[ns * 16 + l16][quad * 8];
            short8 v1 = *(const short8*)&Vts[ns * 16 + l16][32 + quad * 8];
            O[ns] = MFMA(pA0, v0, O[ns]);
            O[ns] = MFMA(pA1, v1, O[ns]);
        }

        if (more) {
            __syncthreads();   // all waves done reading Ks/Vts/Pb
            *(uint4*)&Ks[r][cc]  = kp;
            *(uint4*)&Vts[r][cc] = vp;
            *(uint4*)&Pb[(R0base + t0 + 192 + r) & 255][cc] = pp;
            __syncthreads();
        }
    }

    // ---- finalize: reduce lsum over 16 lanes, O /= l, transpose via Pscr,
    //      coalesced dwordx4 stores ----
    #pragma unroll
    for (int rr = 0; rr < 4; ++rr) {
        float s = lsum[rr];
        s += __shfl_xor(s, 1, 64); s += __shfl_xor(s, 2, 64);
        s += __shfl_xor(s, 4, 64); s += __shfl_xor(s, 8, 64);
        const float inv = 1.0f / s;
        #pragma unroll
        for (int ns = 0; ns < 4; ++ns)
            Pscr[wave][quad * 4 + rr][ns * 16 + l16] = f2bf(O[ns][rr] * inv);
    }
    {
        const ushort_t* src = &Pscr[wave][lane >> 2][(lane & 3) * 16];
        uint4 u0 = *(const uint4*)src;
        uint4 u1 = *(const uint4*)(src + 8);
        const int srow = s0 + wave * 16 + (lane >> 2);
        ushort_t* dst = xg + ((size_t)b * SS + srow) * DD + h * CC + (lane & 3) * 16;
        *(uint4*)dst = u0;
        *(uint4*)(dst + 8) = u1;
    }
}

// ---------------------------------------------------------------------------
extern "C" void kernel_launch(void* const* d_in, const int* in_sizes, int n_in,
                              void* d_out, int out_size, void* d_ws, size_t ws_size,
                              hipStream_t stream)
{
    (void)in_sizes; (void)n_in; (void)out_size; (void)ws_size;

    const float* query = (const float*)d_in[0];
    const float* key_  = (const float*)d_in[1];
    const float* value = (const float*)d_in[2];
    const float* pos   = (const float*)d_in[3];
    const unsigned char* mask = (const unsigned char*)d_in[4];
    const float* Wq   = (const float*)d_in[5];
    const float* bq   = (const float*)d_in[6];
    const float* Wk   = (const float*)d_in[7];
    const float* bk   = (const float*)d_in[8];
    const float* Wv   = (const float*)d_in[9];
    const float* bv   = (const float*)d_in[10];
    const float* Wpos = (const float*)d_in[11];
    const float* Wout = (const float*)d_in[12];
    const float* bout = (const float*)d_in[13];
    const float* ub   = (const float*)d_in[14];
    const float* vb   = (const float*)d_in[15];

    const size_t NBS = (size_t)BB * SS * DD;   // 4194304
    const size_t NP  = (size_t)PP * DD;        // 1048064
    const size_t NW  = (size_t)DD * DD;        // 262144

    ushort_t* wt   = (ushort_t*)d_ws;          // 5 transposed weights
    ushort_t* qu   = wt + 5 * NW;
    ushort_t* qv   = qu + NBS;
    ushort_t* kbuf = qv + NBS;
    ushort_t* vtb  = kbuf + NBS;               // V^T [bh][c][s]
    ushort_t* pbuf = vtb + NBS;                // [h][u][c]
    ushort_t* xg   = pbuf + NP;

    ushort_t* WtO = wt + 4 * NW;

    wtrans_kernel<<<dim3(320), dim3(256), 0, stream>>>(Wq, Wk, Wv, Wpos, Wout, wt);

    qkvpos_kernel<<<dim3(1664), dim3(256), 0, stream>>>(
        query, key_, value, pos, wt, bq, bk, bv, ub, vb,
        qu, qv, kbuf, vtb, pbuf);

    attn_kernel<<<dim3(64, 8), dim3(512), 0, stream>>>(qu, qv, kbuf, vtb, pbuf, mask, xg);

    outproj_kernel<<<dim3(512), dim3(256), 0, stream>>>(xg, WtO, bout, (float*)d_out);
}